// Round 5
// baseline (449.955 us; speedup 1.0000x reference)
//
#include <hip/hip_runtime.h>
#include <cmath>

#define EPSF 1e-6f

// ---------------------------------------------------------------------------
// Shapes: B=1, S=2048, H=16, D=64, hid=1024
// ---------------------------------------------------------------------------

__device__ __forceinline__ float wave_allsum(float v) {
#pragma unroll
  for (int off = 32; off > 0; off >>= 1) v += __shfl_xor(v, off, 64);
  return v;
}

// ---------------- K0: coarse memory = sum of fine banks --------------------
__global__ __launch_bounds__(256) void k0_summem(const float* __restrict__ FM,
    const float* __restrict__ FN, float* __restrict__ MC, float* __restrict__ ZC)
{
  int idx = blockIdx.x * 256 + threadIdx.x;
  if (idx < 65536)
    MC[idx] = FM[idx] + FM[65536 + idx] + FM[131072 + idx] + FM[196608 + idx];
  if (idx < 1024)
    ZC[idx] = FN[idx] + FN[1024 + idx] + FN[2048 + idx] + FN[3072 + idx];
}

// ---------------- generic 64x64-tile f32 GEMM body (N=K=1024) --------------
// act=1 applies elu(x)+1 = x>0 ? x+1 : exp(x)
__device__ __forceinline__ void gemm_body(const float* __restrict__ A,
    const float* __restrict__ B, float* __restrict__ C, int act)
{
  __shared__ __align__(16) float As[32][68];
  __shared__ __align__(16) float Bs[32][68];
  int tid = threadIdx.x;
  int tx = tid & 15, ty = tid >> 4;
  int m0 = blockIdx.y * 64, n0 = blockIdx.x * 64;
  float acc[4][4] = {{0.f}};

  for (int k0 = 0; k0 < 1024; k0 += 32) {
#pragma unroll
    for (int p = 0; p < 2; ++p) {
      int idx = tid + p * 256;            // 0..511
      int am = idx >> 3, akq = idx & 7;   // 64 rows x 8 float4
      float4 a4 = *reinterpret_cast<const float4*>(A + (m0 + am) * 1024 + k0 + akq * 4);
      As[akq * 4 + 0][am] = a4.x; As[akq * 4 + 1][am] = a4.y;
      As[akq * 4 + 2][am] = a4.z; As[akq * 4 + 3][am] = a4.w;
      int bk = idx >> 4, bnq = idx & 15;  // 32 rows x 16 float4
      float4 b4 = *reinterpret_cast<const float4*>(B + (k0 + bk) * 1024 + n0 + bnq * 4);
      *reinterpret_cast<float4*>(&Bs[bk][bnq * 4]) = b4;
    }
    __syncthreads();
#pragma unroll
    for (int kk = 0; kk < 32; ++kk) {
      float4 a4 = *reinterpret_cast<const float4*>(&As[kk][ty * 4]);
      float4 b4 = *reinterpret_cast<const float4*>(&Bs[kk][tx * 4]);
      float av[4] = {a4.x, a4.y, a4.z, a4.w};
      float bv[4] = {b4.x, b4.y, b4.z, b4.w};
#pragma unroll
      for (int i = 0; i < 4; ++i)
#pragma unroll
        for (int j = 0; j < 4; ++j) acc[i][j] += av[i] * bv[j];
    }
    __syncthreads();
  }
#pragma unroll
  for (int i = 0; i < 4; ++i) {
    float v0 = acc[i][0], v1 = acc[i][1], v2 = acc[i][2], v3 = acc[i][3];
    if (act) {
      v0 = v0 > 0.f ? v0 + 1.f : expf(v0);
      v1 = v1 > 0.f ? v1 + 1.f : expf(v1);
      v2 = v2 > 0.f ? v2 + 1.f : expf(v2);
      v3 = v3 > 0.f ? v3 + 1.f : expf(v3);
    }
    float4 o; o.x = v0; o.y = v1; o.z = v2; o.w = v3;
    *reinterpret_cast<float4*>(C + (m0 + ty * 4 + i) * 1024 + n0 + tx * 4) = o;
  }
}

// K1: q/k/v projections fused in grid.z; q,k get elu+1 (-> sigma_q, sigma_k)
__global__ __launch_bounds__(256) void proj_kernel(const float* __restrict__ A,
    const float* __restrict__ Wq, const float* __restrict__ Wk, const float* __restrict__ Wv,
    float* __restrict__ Oq, float* __restrict__ Ok, float* __restrict__ Ov)
{
  int z = blockIdx.z;
  const float* B = (z == 0) ? Wq : (z == 1) ? Wk : Wv;
  float* C = (z == 0) ? Oq : (z == 1) ? Ok : Ov;
  gemm_body(A, B, C, z < 2 ? 1 : 0);
}

// K10: plain GEMM (final output projection)
__global__ __launch_bounds__(256) void gemm_kernel(const float* __restrict__ A,
    const float* __restrict__ B, float* __restrict__ C)
{
  gemm_body(A, B, C, 0);
}

// ---------------- K2: coarse retrieval + relevances ------------------------
// one block = (head h, 64 query rows). out[s][d] = sum_dp sq[s][dp]*Mc[dp][d]
__global__ __launch_bounds__(256) void coarse_kernel(const float* __restrict__ SQ,
    const float* __restrict__ MC, const float* __restrict__ ZC, const float* __restrict__ FN,
    float* __restrict__ CO, float* __restrict__ RELS, float* __restrict__ PARTS)
{
  int h = blockIdx.x, st = blockIdx.y;   // st: 0..31
  int tid = threadIdx.x;
  int s0 = st * 64;
  __shared__ __align__(16) float Mc[64][68];
  __shared__ __align__(16) float sqT[64][68];   // [dp][s_local]
  __shared__ float zf[5][64];                    // z, fn0..3
  __shared__ float relb[5][64];

  for (int idx = tid; idx < 4096; idx += 256) {
    int r = idx >> 6, d = idx & 63;
    Mc[r][d] = MC[h * 4096 + idx];
    sqT[d][r] = SQ[(s0 + r) * 1024 + h * 64 + d];
  }
  // zf staging: 320 elements, strided so ALL are covered (fixed R1 bug:
  // previous version never wrote zf[4] with a 256-thread block)
  for (int idx = tid; idx < 320; idx += 256) {
    int w = idx >> 6, d = idx & 63;
    zf[w][d] = (w == 0) ? ZC[h * 64 + d] : FN[(w - 1) * 1024 + h * 64 + d];
  }
  __syncthreads();

  int tx = tid & 15, sy = tid >> 4;
  float acc[4][4] = {{0.f}};
  for (int dp = 0; dp < 64; ++dp) {
    float4 qv = *reinterpret_cast<const float4*>(&sqT[dp][sy * 4]);
    float4 mv = *reinterpret_cast<const float4*>(&Mc[dp][tx * 4]);
    float qa[4] = {qv.x, qv.y, qv.z, qv.w};
    float mb[4] = {mv.x, mv.y, mv.z, mv.w};
#pragma unroll
    for (int i = 0; i < 4; ++i)
#pragma unroll
      for (int j = 0; j < 4; ++j) acc[i][j] += qa[i] * mb[j];
  }

  // relevance dots: 5 vectors x 64 s
  {
    int s = tid & 63, wh = tid >> 6;
    float r = 0.f;
    for (int dp = 0; dp < 64; ++dp) r += sqT[dp][s] * zf[wh][dp];
    relb[wh][s] = r;
    if (wh == 0) {
      float r4 = 0.f;
      for (int dp = 0; dp < 64; ++dp) r4 += sqT[dp][s] * zf[4][dp];
      relb[4][s] = r4;
    }
  }
  __syncthreads();

#pragma unroll
  for (int i = 0; i < 4; ++i) {
    int s = sy * 4 + i;
    float rc = fmaxf(relb[0][s], EPSF);
    float4 o; o.x = acc[i][0] / rc; o.y = acc[i][1] / rc;
    o.z = acc[i][2] / rc; o.w = acc[i][3] / rc;
    *reinterpret_cast<float4*>(&CO[(s0 + s) * 1024 + h * 64 + tx * 4]) = o;
  }
  if (tid < 64) {
#pragma unroll
    for (int f = 0; f < 4; ++f)
      RELS[f * 32768 + h * 2048 + s0 + tid] = relb[1 + f][tid];
#pragma unroll
    for (int f = 0; f < 4; ++f) {
      float v = wave_allsum(relb[1 + f][tid]);
      if (tid == 0) PARTS[f * 512 + h * 32 + st] = v;
    }
  }
}

// ---------------- K3: expansion-gate MLP ------------------------------------
__global__ __launch_bounds__(256) void eg_kernel(const float* __restrict__ CO,
    const float* __restrict__ W1, const float* __restrict__ B1,
    const float* __restrict__ W2, const float* __restrict__ B2, float* __restrict__ EP)
{
  int tid = threadIdx.x;
  int s0 = blockIdx.x * 8;
  __shared__ __align__(16) float crow[8 * 1024];
  __shared__ float wred[4];
  const float4* src = reinterpret_cast<const float4*>(CO + s0 * 1024);
  float4* dst = reinterpret_cast<float4*>(crow);
  for (int i = tid; i < 2048; i += 256) dst[i] = src[i];
  __syncthreads();

  float acc[8] = {0.f, 0.f, 0.f, 0.f, 0.f, 0.f, 0.f, 0.f};
  float b1 = B1[tid], w2 = W2[tid];
  for (int i = 0; i < 1024; ++i) {
    float w = W1[i * 256 + tid];
#pragma unroll
    for (int s8 = 0; s8 < 8; ++s8) acc[s8] += crow[s8 * 1024 + i] * w;
  }
  int lane = tid & 63, wid = tid >> 6;
  for (int s8 = 0; s8 < 8; ++s8) {
    float v = fmaxf(acc[s8] + b1, 0.f) * w2;
    v = wave_allsum(v);
    if (lane == 0) wred[wid] = v;
    __syncthreads();
    if (tid == 0) {
      float lg = wred[0] + wred[1] + wred[2] + wred[3] + B2[0];
      EP[s0 + s8] = 1.f / (1.f + expf(-lg));
    }
    __syncthreads();
  }
}

// ---------------- K4: bank softmax weights ----------------------------------
__global__ void weights_kernel(const float* __restrict__ P, float* __restrict__ W)
{
  int h = threadIdx.x;
  if (h >= 16) return;
  float r[4];
#pragma unroll
  for (int f = 0; f < 4; ++f) {
    float s = 0.f;
    for (int t = 0; t < 32; ++t) s += P[f * 512 + h * 32 + t];
    r[f] = s * (1.f / 2048.f);
  }
  float m = fmaxf(fmaxf(r[0], r[1]), fmaxf(r[2], r[3]));
  float e0 = expf(r[0] - m), e1 = expf(r[1] - m), e2 = expf(r[2] - m), e3 = expf(r[3] - m);
  float inv = 1.f / (e0 + e1 + e2 + e3);
  W[0 * 16 + h] = e0 * inv; W[1 * 16 + h] = e1 * inv;
  W[2 * 16 + h] = e2 * inv; W[3 * 16 + h] = e3 * inv;
}

// ---------------- K5: fine retrieval + memory combine -----------------------
__global__ __launch_bounds__(256) void fine_combine_kernel(const float* __restrict__ SQ,
    const float* __restrict__ FM, const float* __restrict__ RELS, const float* __restrict__ WT,
    const float* __restrict__ EP, const float* __restrict__ CO, float* __restrict__ MO)
{
  int h = blockIdx.x, st = blockIdx.y;
  int tid = threadIdx.x, d = tid & 63, g = tid >> 6;
  __shared__ float sqr[32][64];
  __shared__ float w4[4];
  if (tid < 4) w4[tid] = WT[tid * 16 + h];
  __syncthreads();

  for (int sb = 0; sb < 128; sb += 32) {
    int s0 = st * 128 + sb;
#pragma unroll
    for (int r = 0; r < 8; ++r)
      sqr[g * 8 + r][d] = SQ[(s0 + g * 8 + r) * 1024 + h * 64 + d];
    __syncthreads();   // LDS write->cross-lane-read ordering (wave-private rows,
                       // but do not rely on lockstep ordering)

    float acc[4][8];
#pragma unroll
    for (int f = 0; f < 4; ++f)
#pragma unroll
      for (int r = 0; r < 8; ++r) acc[f][r] = 0.f;

    for (int dp = 0; dp < 64; ++dp) {
      float m0 = FM[           h * 4096 + dp * 64 + d];
      float m1 = FM[ 65536 +   h * 4096 + dp * 64 + d];
      float m2 = FM[131072 +   h * 4096 + dp * 64 + d];
      float m3 = FM[196608 +   h * 4096 + dp * 64 + d];
#pragma unroll
      for (int r = 0; r < 8; ++r) {
        float qv = sqr[g * 8 + r][dp];
        acc[0][r] += m0 * qv; acc[1][r] += m1 * qv;
        acc[2][r] += m2 * qv; acc[3][r] += m3 * qv;
      }
    }
#pragma unroll
    for (int r = 0; r < 8; ++r) {
      int s = s0 + g * 8 + r;
      float fine = 0.f;
#pragma unroll
      for (int f = 0; f < 4; ++f) {
        float rf = fmaxf(RELS[f * 32768 + h * 2048 + s], EPSF);
        fine += w4[f] * acc[f][r] / rf;
      }
      float e = EP[s];
      float cv = CO[s * 1024 + h * 64 + d];
      MO[s * 1024 + h * 64 + d] = e * fine + (1.f - e) * cv;
    }
    __syncthreads();   // all reads of sqr done before next-iteration overwrite
  }
}

// ---------------- K6: per-chunk KV state sums -------------------------------
__global__ __launch_bounds__(256) void chunk_state_kernel(const float* __restrict__ SK,
    const float* __restrict__ V, float* __restrict__ ST)
{
  int h = blockIdx.x, c = blockIdx.y, tid = threadIdx.x;
  __shared__ __align__(16) float sk[64][68];
  __shared__ __align__(16) float vv[64][68];
  for (int idx = tid; idx < 4096; idx += 256) {
    int s = idx >> 6, d = idx & 63;
    sk[s][d] = SK[(c * 64 + s) * 1024 + h * 64 + d];
    vv[s][d] = V [(c * 64 + s) * 1024 + h * 64 + d];
  }
  __syncthreads();
  int tx = tid & 15, dy = tid >> 4;
  float acc[4][4] = {{0.f}};
  for (int s = 0; s < 64; ++s) {
    float4 kd = *reinterpret_cast<const float4*>(&sk[s][dy * 4]);
    float4 ve = *reinterpret_cast<const float4*>(&vv[s][tx * 4]);
    float ka[4] = {kd.x, kd.y, kd.z, kd.w};
    float vb[4] = {ve.x, ve.y, ve.z, ve.w};
#pragma unroll
    for (int i = 0; i < 4; ++i)
#pragma unroll
      for (int j = 0; j < 4; ++j) acc[i][j] += ka[i] * vb[j];
  }
  float* base = ST + (h * 32 + c) * 4160;
#pragma unroll
  for (int i = 0; i < 4; ++i) {
    float4 o; o.x = acc[i][0]; o.y = acc[i][1]; o.z = acc[i][2]; o.w = acc[i][3];
    *reinterpret_cast<float4*>(&base[(dy * 4 + i) * 64 + tx * 4]) = o;
  }
  if (tid < 64) {
    float ks = 0.f;
    for (int s = 0; s < 64; ++s) ks += sk[s][tid];
    base[4096 + tid] = ks;
  }
}

// ---------------- K7: exclusive prefix over chunks (in place) ---------------
__global__ __launch_bounds__(256) void scan_kernel(float* __restrict__ ST)
{
  int h = blockIdx.x, tid = threadIdx.x;
  for (int idx = tid; idx < 4160; idx += 256) {
    float run = 0.f;
    for (int c = 0; c < 32; ++c) {
      float* p = ST + (h * 32 + c) * 4160 + idx;
      float t = *p; *p = run; run += t;
    }
  }
}

// ---------------- K8: causal linear attention within chunk ------------------
__global__ __launch_bounds__(256) void local_attn_kernel(const float* __restrict__ SQ,
    const float* __restrict__ SK, const float* __restrict__ V,
    const float* __restrict__ ST, float* __restrict__ OUT)
{
  int h = blockIdx.x, c = blockIdx.y, tid = threadIdx.x;
  __shared__ __align__(16) float sqT[64][68];   // [d][s]
  __shared__ __align__(16) float skT[64][68];   // [d][t], later V[t][e]
  __shared__ __align__(16) float buf3[64][68];  // KVprev[d][e], later SC[s][t]
  __shared__ float kprev[64];
  __shared__ float deni[64];
  const float* st = ST + (h * 32 + c) * 4160;

  for (int idx = tid; idx < 4096; idx += 256) {
    int r = idx >> 6, d = idx & 63;
    sqT[d][r] = SQ[(c * 64 + r) * 1024 + h * 64 + d];
    skT[d][r] = SK[(c * 64 + r) * 1024 + h * 64 + d];
    buf3[r][d] = st[idx];                       // KVprev row d=r, col e=d
  }
  if (tid < 64) kprev[tid] = st[4096 + tid];
  __syncthreads();

  int tx = tid & 15, sy = tid >> 4;
  // phase 2: inter-chunk numerator + denominator
  float accn[4][4] = {{0.f}};
  for (int d = 0; d < 64; ++d) {
    float4 qv = *reinterpret_cast<const float4*>(&sqT[d][sy * 4]);
    float4 kv = *reinterpret_cast<const float4*>(&buf3[d][tx * 4]);
    float qa[4] = {qv.x, qv.y, qv.z, qv.w};
    float kb[4] = {kv.x, kv.y, kv.z, kv.w};
#pragma unroll
    for (int i = 0; i < 4; ++i)
#pragma unroll
      for (int j = 0; j < 4; ++j) accn[i][j] += qa[i] * kb[j];
  }
  if (tid < 64) {
    float dv = 0.f;
    for (int d = 0; d < 64; ++d) dv += sqT[d][tid] * kprev[d];
    deni[tid] = dv;
  }
  // phase 3: scores (registers) while buf3 still holds KVprev
  float sc[4][4] = {{0.f}};
  for (int d = 0; d < 64; ++d) {
    float4 qv = *reinterpret_cast<const float4*>(&sqT[d][sy * 4]);
    float4 kt = *reinterpret_cast<const float4*>(&skT[d][tx * 4]);
    float qa[4] = {qv.x, qv.y, qv.z, qv.w};
    float kb[4] = {kt.x, kt.y, kt.z, kt.w};
#pragma unroll
    for (int i = 0; i < 4; ++i)
#pragma unroll
      for (int j = 0; j < 4; ++j) sc[i][j] += qa[i] * kb[j];
  }
  __syncthreads();   // phase-2 reads of buf3 complete
#pragma unroll
  for (int i = 0; i < 4; ++i) {
    int s = sy * 4 + i;
#pragma unroll
    for (int j = 0; j < 4; ++j) {
      int t = tx * 4 + j;
      buf3[s][t] = (t <= s) ? sc[i][j] : 0.f;   // masked scores
    }
  }
  __syncthreads();
  // phase 4: stage V over skT (dead)
  for (int idx = tid; idx < 4096; idx += 256) {
    int r = idx >> 6, d = idx & 63;
    skT[r][d] = V[(c * 64 + r) * 1024 + h * 64 + d];
  }
  __syncthreads();
  // phase 5: intra-chunk accumulate + output
  for (int i = 0; i < 4; ++i) {
    int s = sy * 4 + i;
    float num[4] = {accn[i][0], accn[i][1], accn[i][2], accn[i][3]};
    float den = deni[s];
    for (int tb = 0; tb <= sy; ++tb) {          // upper part of SC is zeroed
      float4 srow = *reinterpret_cast<const float4*>(&buf3[s][tb * 4]);
      float sv[4] = {srow.x, srow.y, srow.z, srow.w};
#pragma unroll
      for (int tt = 0; tt < 4; ++tt) {
        float4 vr = *reinterpret_cast<const float4*>(&skT[tb * 4 + tt][tx * 4]);
        num[0] += sv[tt] * vr.x; num[1] += sv[tt] * vr.y;
        num[2] += sv[tt] * vr.z; num[3] += sv[tt] * vr.w;
        den += sv[tt];
      }
    }
    den = fmaxf(den, EPSF);
    float4 o; o.x = num[0] / den; o.y = num[1] / den; o.z = num[2] / den; o.w = num[3] / den;
    *reinterpret_cast<float4*>(&OUT[(c * 64 + s) * 1024 + h * 64 + tx * 4]) = o;
  }
}

// ---------------- K9: gate combine ------------------------------------------
__global__ __launch_bounds__(256) void combine_kernel(const float* __restrict__ MO,
    const float* __restrict__ LO, const float* __restrict__ MG, float* __restrict__ CB)
{
  int idx = blockIdx.x * 256 + threadIdx.x;
  int hh = (idx >> 6) & 15;
  float g = 1.f / (1.f + expf(-MG[hh]));
  CB[idx] = g * MO[idx] + (1.f - g) * LO[idx];
}

// ---------------------------------------------------------------------------
extern "C" void kernel_launch(void* const* d_in, const int* in_sizes, int n_in,
                              void* d_out, int out_size, void* d_ws, size_t ws_size,
                              hipStream_t stream)
{
  const float* hs   = (const float*)d_in[0];
  const float* wq   = (const float*)d_in[1];
  const float* wk   = (const float*)d_in[2];
  const float* wv   = (const float*)d_in[3];
  const float* wo   = (const float*)d_in[4];
  const float* mg   = (const float*)d_in[5];
  const float* egw1 = (const float*)d_in[6];
  const float* egb1 = (const float*)d_in[7];
  const float* egw2 = (const float*)d_in[8];
  const float* egb2 = (const float*)d_in[9];
  const float* fm   = (const float*)d_in[10];
  const float* fn   = (const float*)d_in[11];
  float* out = (float*)d_out;

  float* ws     = (float*)d_ws;
  float* sq     = ws;                   // sigma_q        [2048][1024]
  float* sk     = sq + 2097152;         // sigma_k        [2048][1024]
  float* vv     = sk + 2097152;         // v              [2048][1024]
  float* co     = vv + 2097152;         // output_coarse  [2048][1024]
  float* mo     = co + 2097152;         // memory_output  [2048][1024]
  float* lo     = mo + 2097152;         // local_output   [2048][1024]
  float* mc     = lo + 2097152;         // M_coarse       [16][64][64]
  float* zc     = mc + 65536;           // z_coarse       [16][64]
  float* rels   = zc + 1024;            // rels           [4][16][2048]
  float* parts  = rels + 131072;        // partial sums   [4][16][32]
  float* wts    = parts + 2048;         // weights        [4][16]
  float* ep     = wts + 64;             // expansion prob [2048]
  float* states = ep + 2048;            // chunk states   [16][32][4160]
  float* cb     = sk;                   // combined aliases sigma_k (dead by then)

  k0_summem<<<256, 256, 0, stream>>>(fm, fn, mc, zc);
  proj_kernel<<<dim3(16, 32, 3), 256, 0, stream>>>(hs, wq, wk, wv, sq, sk, vv);
  coarse_kernel<<<dim3(16, 32), 256, 0, stream>>>(sq, mc, zc, fn, co, rels, parts);
  eg_kernel<<<256, 256, 0, stream>>>(co, egw1, egb1, egw2, egb2, ep);
  weights_kernel<<<1, 64, 0, stream>>>(parts, wts);
  fine_combine_kernel<<<dim3(16, 16), 256, 0, stream>>>(sq, fm, rels, wts, ep, co, mo);
  chunk_state_kernel<<<dim3(16, 32), 256, 0, stream>>>(sk, vv, states);
  scan_kernel<<<16, 256, 0, stream>>>(states);
  local_attn_kernel<<<dim3(16, 32), 256, 0, stream>>>(sq, sk, vv, states, lo);
  combine_kernel<<<8192, 256, 0, stream>>>(mo, lo, mg, cb);
  gemm_kernel<<<dim3(16, 32), 256, 0, stream>>>(cb, wo, out);
}

// Round 6
// 297.501 us; speedup vs baseline: 1.5125x; 1.5125x over previous
//
#include <hip/hip_runtime.h>
#include <cmath>

#define EPSF 1e-6f

// ---------------------------------------------------------------------------
// Shapes: B=1, S=2048, H=16, D=64, hid=1024
// Round 5->6: QKV projection + output projection moved to bf16 MFMA
// (mfma_f32_16x16x32_bf16, fp32 accumulate). Everything else fp32 unchanged.
// ---------------------------------------------------------------------------

typedef __attribute__((ext_vector_type(8))) short bf16x8;   // 8 bf16 = 4 VGPR
typedef __attribute__((ext_vector_type(4))) float f32x4;    // MFMA C/D
typedef __attribute__((ext_vector_type(8))) unsigned short u16x8;

__device__ __forceinline__ float wave_allsum(float v) {
#pragma unroll
  for (int off = 32; off > 0; off >>= 1) v += __shfl_xor(v, off, 64);
  return v;
}

__device__ __forceinline__ unsigned short f2bf(float f) {  // RNE f32->bf16
  unsigned int u = __float_as_uint(f);
  unsigned int r = (u + 0x7fffu + ((u >> 16) & 1u)) >> 16;
  return (unsigned short)r;
}

// ---------------- K0: coarse memory = sum of fine banks --------------------
__global__ __launch_bounds__(256) void k0_summem(const float* __restrict__ FM,
    const float* __restrict__ FN, float* __restrict__ MC, float* __restrict__ ZC)
{
  int idx = blockIdx.x * 256 + threadIdx.x;
  if (idx < 65536)
    MC[idx] = FM[idx] + FM[65536 + idx] + FM[131072 + idx] + FM[196608 + idx];
  if (idx < 1024)
    ZC[idx] = FN[idx] + FN[1024 + idx] + FN[2048 + idx] + FN[3072 + idx];
}

// ---------------- cast kernels ---------------------------------------------
// flat f32 -> bf16, 4 elements/thread
__global__ __launch_bounds__(256) void cast_bf16_k(const float* __restrict__ X,
    unsigned short* __restrict__ Y)
{
  int i = blockIdx.x * 256 + threadIdx.x;
  float4 v = *reinterpret_cast<const float4*>(X + i * 4);
  ushort4 o; o.x = f2bf(v.x); o.y = f2bf(v.y); o.z = f2bf(v.z); o.w = f2bf(v.w);
  *reinterpret_cast<ushort4*>(Y + i * 4) = o;
}

// W [1024][1024] f32 row-major (k,n) -> WT [1024][1024] bf16 (n,k)
__global__ __launch_bounds__(256) void cast_transpose_k(const float* __restrict__ W,
    unsigned short* __restrict__ WT)
{
  __shared__ float tile[64][65];
  int n0 = blockIdx.x * 64, k0 = blockIdx.y * 64;
  int tid = threadIdx.x;
  for (int i = tid; i < 4096; i += 256) {
    int r = i >> 6, c = i & 63;            // r = k-local, c = n-local
    tile[r][c] = W[(k0 + r) * 1024 + n0 + c];
  }
  __syncthreads();
  for (int i = tid; i < 1024; i += 256) {
    int r = i >> 4, c4 = (i & 15) * 4;     // r = n-local, c4 = k-local
    ushort4 o;
    o.x = f2bf(tile[c4 + 0][r]); o.y = f2bf(tile[c4 + 1][r]);
    o.z = f2bf(tile[c4 + 2][r]); o.w = f2bf(tile[c4 + 3][r]);
    *reinterpret_cast<ushort4*>(&WT[(n0 + r) * 1024 + k0 + c4]) = o;
  }
}

// ---------------- bf16 MFMA GEMM: C[M][1024] = A[M][1024] x BT[1024][1024]^T
// 128x128 tile, 4 waves (2x2, each 64x64 = 4x4 frags of 16x16), BK=64.
// act=1 applies elu(x)+1 in epilogue.
#define LDK 72   // 64 + 8 bf16 pad: stride 144 B (16B-aligned, 2-way banks)

__global__ __launch_bounds__(256) void mm_bf16(const unsigned short* __restrict__ A,
    const unsigned short* __restrict__ BT, float* __restrict__ C, int act)
{
  __shared__ unsigned short As[128 * LDK];
  __shared__ unsigned short Bs[128 * LDK];
  int tid = threadIdx.x;
  int m0 = blockIdx.y * 128, n0 = blockIdx.x * 128;
  int wid = tid >> 6, lane = tid & 63;
  int wr = wid >> 1, wc = wid & 1;       // 2x2 wave grid
  int lr = lane & 15, lg = lane >> 4;    // frag row/col, k-group

  f32x4 acc[4][4];
#pragma unroll
  for (int m = 0; m < 4; ++m)
#pragma unroll
    for (int n = 0; n < 4; ++n)
#pragma unroll
      for (int r = 0; r < 4; ++r) acc[m][n][r] = 0.f;

  for (int kt = 0; kt < 16; ++kt) {
    int k0 = kt * 64;
#pragma unroll
    for (int p = 0; p < 4; ++p) {
      int c = p * 256 + tid;             // 0..1023 chunks of 8 bf16
      int row = c >> 3, k8 = c & 7;
      u16x8 va = *reinterpret_cast<const u16x8*>(A + (m0 + row) * 1024 + k0 + k8 * 8);
      *reinterpret_cast<u16x8*>(&As[row * LDK + k8 * 8]) = va;
      u16x8 vb = *reinterpret_cast<const u16x8*>(BT + (n0 + row) * 1024 + k0 + k8 * 8);
      *reinterpret_cast<u16x8*>(&Bs[row * LDK + k8 * 8]) = vb;
    }
    __syncthreads();
#pragma unroll
    for (int kk = 0; kk < 2; ++kk) {
      bf16x8 af[4], bfr[4];
#pragma unroll
      for (int m = 0; m < 4; ++m)
        af[m] = *reinterpret_cast<const bf16x8*>(&As[(wr * 64 + m * 16 + lr) * LDK + kk * 32 + lg * 8]);
#pragma unroll
      for (int n = 0; n < 4; ++n)
        bfr[n] = *reinterpret_cast<const bf16x8*>(&Bs[(wc * 64 + n * 16 + lr) * LDK + kk * 32 + lg * 8]);
#pragma unroll
      for (int m = 0; m < 4; ++m)
#pragma unroll
        for (int n = 0; n < 4; ++n)
          acc[m][n] = __builtin_amdgcn_mfma_f32_16x16x32_bf16(af[m], bfr[n], acc[m][n], 0, 0, 0);
    }
    __syncthreads();
  }
  // epilogue: C/D mapping col=lane&15, row=(lane>>4)*4+reg  [guide m89-verified]
#pragma unroll
  for (int m = 0; m < 4; ++m)
#pragma unroll
    for (int n = 0; n < 4; ++n)
#pragma unroll
      for (int r = 0; r < 4; ++r) {
        float v = acc[m][n][r];
        if (act) v = v > 0.f ? v + 1.f : expf(v);
        C[(m0 + wr * 64 + m * 16 + lg * 4 + r) * 1024 + n0 + wc * 64 + n * 16 + lr] = v;
      }
}

// fused QKV: z selects weight/output/activation
__global__ __launch_bounds__(256) void proj_bf16(const unsigned short* __restrict__ A,
    const unsigned short* __restrict__ WqT, const unsigned short* __restrict__ WkT,
    const unsigned short* __restrict__ WvT,
    float* __restrict__ Oq, float* __restrict__ Ok, float* __restrict__ Ov)
{
  // delegate per z (same body as mm_bf16 via direct call pattern)
  int z = blockIdx.z;
  const unsigned short* BT = (z == 0) ? WqT : (z == 1) ? WkT : WvT;
  float* C = (z == 0) ? Oq : (z == 1) ? Ok : Ov;

  __shared__ unsigned short As[128 * LDK];
  __shared__ unsigned short Bs[128 * LDK];
  int tid = threadIdx.x;
  int m0 = blockIdx.y * 128, n0 = blockIdx.x * 128;
  int wid = tid >> 6, lane = tid & 63;
  int wr = wid >> 1, wc = wid & 1;
  int lr = lane & 15, lg = lane >> 4;
  int act = (z < 2) ? 1 : 0;

  f32x4 acc[4][4];
#pragma unroll
  for (int m = 0; m < 4; ++m)
#pragma unroll
    for (int n = 0; n < 4; ++n)
#pragma unroll
      for (int r = 0; r < 4; ++r) acc[m][n][r] = 0.f;

  for (int kt = 0; kt < 16; ++kt) {
    int k0 = kt * 64;
#pragma unroll
    for (int p = 0; p < 4; ++p) {
      int c = p * 256 + tid;
      int row = c >> 3, k8 = c & 7;
      u16x8 va = *reinterpret_cast<const u16x8*>(A + (m0 + row) * 1024 + k0 + k8 * 8);
      *reinterpret_cast<u16x8*>(&As[row * LDK + k8 * 8]) = va;
      u16x8 vb = *reinterpret_cast<const u16x8*>(BT + (n0 + row) * 1024 + k0 + k8 * 8);
      *reinterpret_cast<u16x8*>(&Bs[row * LDK + k8 * 8]) = vb;
    }
    __syncthreads();
#pragma unroll
    for (int kk = 0; kk < 2; ++kk) {
      bf16x8 af[4], bfr[4];
#pragma unroll
      for (int m = 0; m < 4; ++m)
        af[m] = *reinterpret_cast<const bf16x8*>(&As[(wr * 64 + m * 16 + lr) * LDK + kk * 32 + lg * 8]);
#pragma unroll
      for (int n = 0; n < 4; ++n)
        bfr[n] = *reinterpret_cast<const bf16x8*>(&Bs[(wc * 64 + n * 16 + lr) * LDK + kk * 32 + lg * 8]);
#pragma unroll
      for (int m = 0; m < 4; ++m)
#pragma unroll
        for (int n = 0; n < 4; ++n)
          acc[m][n] = __builtin_amdgcn_mfma_f32_16x16x32_bf16(af[m], bfr[n], acc[m][n], 0, 0, 0);
    }
    __syncthreads();
  }
#pragma unroll
  for (int m = 0; m < 4; ++m)
#pragma unroll
    for (int n = 0; n < 4; ++n)
#pragma unroll
      for (int r = 0; r < 4; ++r) {
        float v = acc[m][n][r];
        if (act) v = v > 0.f ? v + 1.f : expf(v);
        C[(m0 + wr * 64 + m * 16 + lg * 4 + r) * 1024 + n0 + wc * 64 + n * 16 + lr] = v;
      }
}

// ---------------- K2: coarse retrieval + relevances ------------------------
__global__ __launch_bounds__(256) void coarse_kernel(const float* __restrict__ SQ,
    const float* __restrict__ MC, const float* __restrict__ ZC, const float* __restrict__ FN,
    float* __restrict__ CO, float* __restrict__ RELS, float* __restrict__ PARTS)
{
  int h = blockIdx.x, st = blockIdx.y;
  int tid = threadIdx.x;
  int s0 = st * 64;
  __shared__ __align__(16) float Mc[64][68];
  __shared__ __align__(16) float sqT[64][68];
  __shared__ float zf[5][64];
  __shared__ float relb[5][64];

  for (int idx = tid; idx < 4096; idx += 256) {
    int r = idx >> 6, d = idx & 63;
    Mc[r][d] = MC[h * 4096 + idx];
    sqT[d][r] = SQ[(s0 + r) * 1024 + h * 64 + d];
  }
  for (int idx = tid; idx < 320; idx += 256) {
    int w = idx >> 6, d = idx & 63;
    zf[w][d] = (w == 0) ? ZC[h * 64 + d] : FN[(w - 1) * 1024 + h * 64 + d];
  }
  __syncthreads();

  int tx = tid & 15, sy = tid >> 4;
  float acc[4][4] = {{0.f}};
  for (int dp = 0; dp < 64; ++dp) {
    float4 qv = *reinterpret_cast<const float4*>(&sqT[dp][sy * 4]);
    float4 mv = *reinterpret_cast<const float4*>(&Mc[dp][tx * 4]);
    float qa[4] = {qv.x, qv.y, qv.z, qv.w};
    float mb[4] = {mv.x, mv.y, mv.z, mv.w};
#pragma unroll
    for (int i = 0; i < 4; ++i)
#pragma unroll
      for (int j = 0; j < 4; ++j) acc[i][j] += qa[i] * mb[j];
  }
  {
    int s = tid & 63, wh = tid >> 6;
    float r = 0.f;
    for (int dp = 0; dp < 64; ++dp) r += sqT[dp][s] * zf[wh][dp];
    relb[wh][s] = r;
    if (wh == 0) {
      float r4 = 0.f;
      for (int dp = 0; dp < 64; ++dp) r4 += sqT[dp][s] * zf[4][dp];
      relb[4][s] = r4;
    }
  }
  __syncthreads();

#pragma unroll
  for (int i = 0; i < 4; ++i) {
    int s = sy * 4 + i;
    float rc = fmaxf(relb[0][s], EPSF);
    float4 o; o.x = acc[i][0] / rc; o.y = acc[i][1] / rc;
    o.z = acc[i][2] / rc; o.w = acc[i][3] / rc;
    *reinterpret_cast<float4*>(&CO[(s0 + s) * 1024 + h * 64 + tx * 4]) = o;
  }
  if (tid < 64) {
#pragma unroll
    for (int f = 0; f < 4; ++f)
      RELS[f * 32768 + h * 2048 + s0 + tid] = relb[1 + f][tid];
#pragma unroll
    for (int f = 0; f < 4; ++f) {
      float v = wave_allsum(relb[1 + f][tid]);
      if (tid == 0) PARTS[f * 512 + h * 32 + st] = v;
    }
  }
}

// ---------------- K3: expansion-gate MLP ------------------------------------
__global__ __launch_bounds__(256) void eg_kernel(const float* __restrict__ CO,
    const float* __restrict__ W1, const float* __restrict__ B1,
    const float* __restrict__ W2, const float* __restrict__ B2, float* __restrict__ EP)
{
  int tid = threadIdx.x;
  int s0 = blockIdx.x * 8;
  __shared__ __align__(16) float crow[8 * 1024];
  __shared__ float wred[4];
  const float4* src = reinterpret_cast<const float4*>(CO + s0 * 1024);
  float4* dst = reinterpret_cast<float4*>(crow);
  for (int i = tid; i < 2048; i += 256) dst[i] = src[i];
  __syncthreads();

  float acc[8] = {0.f, 0.f, 0.f, 0.f, 0.f, 0.f, 0.f, 0.f};
  float b1 = B1[tid], w2 = W2[tid];
  for (int i = 0; i < 1024; ++i) {
    float w = W1[i * 256 + tid];
#pragma unroll
    for (int s8 = 0; s8 < 8; ++s8) acc[s8] += crow[s8 * 1024 + i] * w;
  }
  int lane = tid & 63, wid = tid >> 6;
  for (int s8 = 0; s8 < 8; ++s8) {
    float v = fmaxf(acc[s8] + b1, 0.f) * w2;
    v = wave_allsum(v);
    if (lane == 0) wred[wid] = v;
    __syncthreads();
    if (tid == 0) {
      float lg = wred[0] + wred[1] + wred[2] + wred[3] + B2[0];
      EP[s0 + s8] = 1.f / (1.f + expf(-lg));
    }
    __syncthreads();
  }
}

// ---------------- K4: bank softmax weights ----------------------------------
__global__ void weights_kernel(const float* __restrict__ P, float* __restrict__ W)
{
  int h = threadIdx.x;
  if (h >= 16) return;
  float r[4];
#pragma unroll
  for (int f = 0; f < 4; ++f) {
    float s = 0.f;
    for (int t = 0; t < 32; ++t) s += P[f * 512 + h * 32 + t];
    r[f] = s * (1.f / 2048.f);
  }
  float m = fmaxf(fmaxf(r[0], r[1]), fmaxf(r[2], r[3]));
  float e0 = expf(r[0] - m), e1 = expf(r[1] - m), e2 = expf(r[2] - m), e3 = expf(r[3] - m);
  float inv = 1.f / (e0 + e1 + e2 + e3);
  W[0 * 16 + h] = e0 * inv; W[1 * 16 + h] = e1 * inv;
  W[2 * 16 + h] = e2 * inv; W[3 * 16 + h] = e3 * inv;
}

// ---------------- K5: fine retrieval + memory combine -----------------------
__global__ __launch_bounds__(256) void fine_combine_kernel(const float* __restrict__ SQ,
    const float* __restrict__ FM, const float* __restrict__ RELS, const float* __restrict__ WT,
    const float* __restrict__ EP, const float* __restrict__ CO, float* __restrict__ MO)
{
  int h = blockIdx.x, st = blockIdx.y;
  int tid = threadIdx.x, d = tid & 63, g = tid >> 6;
  __shared__ float sqr[32][64];
  __shared__ float w4[4];
  if (tid < 4) w4[tid] = WT[tid * 16 + h];
  __syncthreads();

  for (int sb = 0; sb < 128; sb += 32) {
    int s0 = st * 128 + sb;
#pragma unroll
    for (int r = 0; r < 8; ++r)
      sqr[g * 8 + r][d] = SQ[(s0 + g * 8 + r) * 1024 + h * 64 + d];
    __syncthreads();

    float acc[4][8];
#pragma unroll
    for (int f = 0; f < 4; ++f)
#pragma unroll
      for (int r = 0; r < 8; ++r) acc[f][r] = 0.f;

    for (int dp = 0; dp < 64; ++dp) {
      float m0 = FM[           h * 4096 + dp * 64 + d];
      float m1 = FM[ 65536 +   h * 4096 + dp * 64 + d];
      float m2 = FM[131072 +   h * 4096 + dp * 64 + d];
      float m3 = FM[196608 +   h * 4096 + dp * 64 + d];
#pragma unroll
      for (int r = 0; r < 8; ++r) {
        float qv = sqr[g * 8 + r][dp];
        acc[0][r] += m0 * qv; acc[1][r] += m1 * qv;
        acc[2][r] += m2 * qv; acc[3][r] += m3 * qv;
      }
    }
#pragma unroll
    for (int r = 0; r < 8; ++r) {
      int s = s0 + g * 8 + r;
      float fine = 0.f;
#pragma unroll
      for (int f = 0; f < 4; ++f) {
        float rf = fmaxf(RELS[f * 32768 + h * 2048 + s], EPSF);
        fine += w4[f] * acc[f][r] / rf;
      }
      float e = EP[s];
      float cv = CO[s * 1024 + h * 64 + d];
      MO[s * 1024 + h * 64 + d] = e * fine + (1.f - e) * cv;
    }
    __syncthreads();
  }
}

// ---------------- K6: per-chunk KV state sums -------------------------------
__global__ __launch_bounds__(256) void chunk_state_kernel(const float* __restrict__ SK,
    const float* __restrict__ V, float* __restrict__ ST)
{
  int h = blockIdx.x, c = blockIdx.y, tid = threadIdx.x;
  __shared__ __align__(16) float sk[64][68];
  __shared__ __align__(16) float vv[64][68];
  for (int idx = tid; idx < 4096; idx += 256) {
    int s = idx >> 6, d = idx & 63;
    sk[s][d] = SK[(c * 64 + s) * 1024 + h * 64 + d];
    vv[s][d] = V [(c * 64 + s) * 1024 + h * 64 + d];
  }
  __syncthreads();
  int tx = tid & 15, dy = tid >> 4;
  float acc[4][4] = {{0.f}};
  for (int s = 0; s < 64; ++s) {
    float4 kd = *reinterpret_cast<const float4*>(&sk[s][dy * 4]);
    float4 ve = *reinterpret_cast<const float4*>(&vv[s][tx * 4]);
    float ka[4] = {kd.x, kd.y, kd.z, kd.w};
    float vb[4] = {ve.x, ve.y, ve.z, ve.w};
#pragma unroll
    for (int i = 0; i < 4; ++i)
#pragma unroll
      for (int j = 0; j < 4; ++j) acc[i][j] += ka[i] * vb[j];
  }
  float* base = ST + (h * 32 + c) * 4160;
#pragma unroll
  for (int i = 0; i < 4; ++i) {
    float4 o; o.x = acc[i][0]; o.y = acc[i][1]; o.z = acc[i][2]; o.w = acc[i][3];
    *reinterpret_cast<float4*>(&base[(dy * 4 + i) * 64 + tx * 4]) = o;
  }
  if (tid < 64) {
    float ks = 0.f;
    for (int s = 0; s < 64; ++s) ks += sk[s][tid];
    base[4096 + tid] = ks;
  }
}

// ---------------- K7: exclusive prefix over chunks (in place) ---------------
__global__ __launch_bounds__(256) void scan_kernel(float* __restrict__ ST)
{
  int h = blockIdx.x, tid = threadIdx.x;
  for (int idx = tid; idx < 4160; idx += 256) {
    float run = 0.f;
    for (int c = 0; c < 32; ++c) {
      float* p = ST + (h * 32 + c) * 4160 + idx;
      float t = *p; *p = run; run += t;
    }
  }
}

// ---------------- K8: causal linear attention within chunk ------------------
__global__ __launch_bounds__(256) void local_attn_kernel(const float* __restrict__ SQ,
    const float* __restrict__ SK, const float* __restrict__ V,
    const float* __restrict__ ST, float* __restrict__ OUT)
{
  int h = blockIdx.x, c = blockIdx.y, tid = threadIdx.x;
  __shared__ __align__(16) float sqT[64][68];
  __shared__ __align__(16) float skT[64][68];
  __shared__ __align__(16) float buf3[64][68];
  __shared__ float kprev[64];
  __shared__ float deni[64];
  const float* st = ST + (h * 32 + c) * 4160;

  for (int idx = tid; idx < 4096; idx += 256) {
    int r = idx >> 6, d = idx & 63;
    sqT[d][r] = SQ[(c * 64 + r) * 1024 + h * 64 + d];
    skT[d][r] = SK[(c * 64 + r) * 1024 + h * 64 + d];
    buf3[r][d] = st[idx];
  }
  if (tid < 64) kprev[tid] = st[4096 + tid];
  __syncthreads();

  int tx = tid & 15, sy = tid >> 4;
  float accn[4][4] = {{0.f}};
  for (int d = 0; d < 64; ++d) {
    float4 qv = *reinterpret_cast<const float4*>(&sqT[d][sy * 4]);
    float4 kv = *reinterpret_cast<const float4*>(&buf3[d][tx * 4]);
    float qa[4] = {qv.x, qv.y, qv.z, qv.w};
    float kb[4] = {kv.x, kv.y, kv.z, kv.w};
#pragma unroll
    for (int i = 0; i < 4; ++i)
#pragma unroll
      for (int j = 0; j < 4; ++j) accn[i][j] += qa[i] * kb[j];
  }
  if (tid < 64) {
    float dv = 0.f;
    for (int d = 0; d < 64; ++d) dv += sqT[d][tid] * kprev[d];
    deni[tid] = dv;
  }
  float sc[4][4] = {{0.f}};
  for (int d = 0; d < 64; ++d) {
    float4 qv = *reinterpret_cast<const float4*>(&sqT[d][sy * 4]);
    float4 kt = *reinterpret_cast<const float4*>(&skT[d][tx * 4]);
    float qa[4] = {qv.x, qv.y, qv.z, qv.w};
    float kb[4] = {kt.x, kt.y, kt.z, kt.w};
#pragma unroll
    for (int i = 0; i < 4; ++i)
#pragma unroll
      for (int j = 0; j < 4; ++j) sc[i][j] += qa[i] * kb[j];
  }
  __syncthreads();
#pragma unroll
  for (int i = 0; i < 4; ++i) {
    int s = sy * 4 + i;
#pragma unroll
    for (int j = 0; j < 4; ++j) {
      int t = tx * 4 + j;
      buf3[s][t] = (t <= s) ? sc[i][j] : 0.f;
    }
  }
  __syncthreads();
  for (int idx = tid; idx < 4096; idx += 256) {
    int r = idx >> 6, d = idx & 63;
    skT[r][d] = V[(c * 64 + r) * 1024 + h * 64 + d];
  }
  __syncthreads();
  for (int i = 0; i < 4; ++i) {
    int s = sy * 4 + i;
    float num[4] = {accn[i][0], accn[i][1], accn[i][2], accn[i][3]};
    float den = deni[s];
    for (int tb = 0; tb <= sy; ++tb) {
      float4 srow = *reinterpret_cast<const float4*>(&buf3[s][tb * 4]);
      float sv[4] = {srow.x, srow.y, srow.z, srow.w};
#pragma unroll
      for (int tt = 0; tt < 4; ++tt) {
        float4 vr = *reinterpret_cast<const float4*>(&skT[tb * 4 + tt][tx * 4]);
        num[0] += sv[tt] * vr.x; num[1] += sv[tt] * vr.y;
        num[2] += sv[tt] * vr.z; num[3] += sv[tt] * vr.w;
        den += sv[tt];
      }
    }
    den = fmaxf(den, EPSF);
    float4 o; o.x = num[0] / den; o.y = num[1] / den; o.z = num[2] / den; o.w = num[3] / den;
    *reinterpret_cast<float4*>(&OUT[(c * 64 + s) * 1024 + h * 64 + tx * 4]) = o;
  }
}

// ---------------- K9: gate combine ------------------------------------------
__global__ __launch_bounds__(256) void combine_kernel(const float* __restrict__ MO,
    const float* __restrict__ LO, const float* __restrict__ MG, float* __restrict__ CB)
{
  int idx = blockIdx.x * 256 + threadIdx.x;
  int hh = (idx >> 6) & 15;
  float g = 1.f / (1.f + expf(-MG[hh]));
  CB[idx] = g * MO[idx] + (1.f - g) * LO[idx];
}

// ---------------------------------------------------------------------------
extern "C" void kernel_launch(void* const* d_in, const int* in_sizes, int n_in,
                              void* d_out, int out_size, void* d_ws, size_t ws_size,
                              hipStream_t stream)
{
  const float* hs   = (const float*)d_in[0];
  const float* wq   = (const float*)d_in[1];
  const float* wk   = (const float*)d_in[2];
  const float* wv   = (const float*)d_in[3];
  const float* wo   = (const float*)d_in[4];
  const float* mg   = (const float*)d_in[5];
  const float* egw1 = (const float*)d_in[6];
  const float* egb1 = (const float*)d_in[7];
  const float* egw2 = (const float*)d_in[8];
  const float* egb2 = (const float*)d_in[9];
  const float* fm   = (const float*)d_in[10];
  const float* fn   = (const float*)d_in[11];
  float* out = (float*)d_out;

  float* ws     = (float*)d_ws;
  float* sq     = ws;                   // sigma_q        [2048][1024] f32
  float* sk     = sq + 2097152;         // sigma_k        [2048][1024]
  float* vv     = sk + 2097152;         // v              [2048][1024]
  float* co     = vv + 2097152;         // output_coarse  [2048][1024]
  float* mo     = co + 2097152;         // memory_output  [2048][1024]
  float* lo     = mo + 2097152;         // local_output   [2048][1024]
  float* mc     = lo + 2097152;         // M_coarse       [16][64][64]
  float* zc     = mc + 65536;           // z_coarse       [16][64]
  float* rels   = zc + 1024;            // rels           [4][16][2048]
  float* parts  = rels + 131072;        // partial sums   [4][16][32]
  float* wts    = parts + 2048;         // weights        [4][16]
  float* ep     = wts + 64;             // expansion prob [2048]
  float* states = ep + 2048;            // chunk states   [16][32][4160]
  float* cb     = sk;                   // combined aliases sigma_k (dead by then)

  // bf16 buffers alias dead-at-use fp32 regions (stream-order safe):
  unsigned short* hsb = (unsigned short*)co;            // hs bf16 [2048][1024]; co written later
  unsigned short* wqT = (unsigned short*)mo;            // [1024][1024] bf16 each
  unsigned short* wkT = wqT + 1048576;                  // mo written by fine_combine later
  unsigned short* wvT = wkT + 1048576;
  unsigned short* woT = (unsigned short*)lo;            // cast after combine reads lo
  unsigned short* cbb = (unsigned short*)sq;            // cast after local_attn reads sq

  k0_summem<<<256, 256, 0, stream>>>(fm, fn, mc, zc);
  cast_bf16_k<<<2048, 256, 0, stream>>>(hs, hsb);
  cast_transpose_k<<<dim3(16, 16), 256, 0, stream>>>(wq, wqT);
  cast_transpose_k<<<dim3(16, 16), 256, 0, stream>>>(wk, wkT);
  cast_transpose_k<<<dim3(16, 16), 256, 0, stream>>>(wv, wvT);
  proj_bf16<<<dim3(8, 16, 3), 256, 0, stream>>>(hsb, wqT, wkT, wvT, sq, sk, vv);
  coarse_kernel<<<dim3(16, 32), 256, 0, stream>>>(sq, mc, zc, fn, co, rels, parts);
  eg_kernel<<<256, 256, 0, stream>>>(co, egw1, egb1, egw2, egb2, ep);
  weights_kernel<<<1, 64, 0, stream>>>(parts, wts);
  fine_combine_kernel<<<dim3(16, 16), 256, 0, stream>>>(sq, fm, rels, wts, ep, co, mo);
  chunk_state_kernel<<<dim3(16, 32), 256, 0, stream>>>(sk, vv, states);
  scan_kernel<<<16, 256, 0, stream>>>(states);
  local_attn_kernel<<<dim3(16, 32), 256, 0, stream>>>(sq, sk, vv, states, lo);
  combine_kernel<<<8192, 256, 0, stream>>>(mo, lo, mg, cb);
  cast_bf16_k<<<2048, 256, 0, stream>>>(cb, cbb);
  cast_transpose_k<<<dim3(16, 16), 256, 0, stream>>>(wo, woT);
  mm_bf16<<<dim3(8, 16), 256, 0, stream>>>(cbb, woT, out, 0);
}

// Round 7
// 255.343 us; speedup vs baseline: 1.7622x; 1.1651x over previous
//
#include <hip/hip_runtime.h>
#include <cmath>

#define EPSF 1e-6f

// ---------------------------------------------------------------------------
// Shapes: B=1, S=2048, H=16, D=64, hid=1024
// R6: QKV + out-proj on bf16 MFMA. R7: eg MLP stage-1 -> bf16 MFMA GEMM
// (was 1 block/CU latency-bound fp32, 85-118 us).
// ---------------------------------------------------------------------------

typedef __attribute__((ext_vector_type(8))) short bf16x8;
typedef __attribute__((ext_vector_type(4))) float f32x4;
typedef __attribute__((ext_vector_type(8))) unsigned short u16x8;

__device__ __forceinline__ float wave_allsum(float v) {
#pragma unroll
  for (int off = 32; off > 0; off >>= 1) v += __shfl_xor(v, off, 64);
  return v;
}

__device__ __forceinline__ unsigned short f2bf(float f) {  // RNE f32->bf16
  unsigned int u = __float_as_uint(f);
  unsigned int r = (u + 0x7fffu + ((u >> 16) & 1u)) >> 16;
  return (unsigned short)r;
}

// ---------------- K0: coarse memory = sum of fine banks --------------------
__global__ __launch_bounds__(256) void k0_summem(const float* __restrict__ FM,
    const float* __restrict__ FN, float* __restrict__ MC, float* __restrict__ ZC)
{
  int idx = blockIdx.x * 256 + threadIdx.x;
  if (idx < 65536)
    MC[idx] = FM[idx] + FM[65536 + idx] + FM[131072 + idx] + FM[196608 + idx];
  if (idx < 1024)
    ZC[idx] = FN[idx] + FN[1024 + idx] + FN[2048 + idx] + FN[3072 + idx];
}

// ---------------- cast kernels ---------------------------------------------
__global__ __launch_bounds__(256) void cast_bf16_k(const float* __restrict__ X,
    unsigned short* __restrict__ Y)
{
  int i = blockIdx.x * 256 + threadIdx.x;
  float4 v = *reinterpret_cast<const float4*>(X + i * 4);
  ushort4 o; o.x = f2bf(v.x); o.y = f2bf(v.y); o.z = f2bf(v.z); o.w = f2bf(v.w);
  *reinterpret_cast<ushort4*>(Y + i * 4) = o;
}

// W [1024][N] f32 row-major -> WT [N][1024] bf16. grid (N/64, 16).
__global__ __launch_bounds__(256) void cast_transpose_k(const float* __restrict__ W,
    unsigned short* __restrict__ WT, int N)
{
  __shared__ float tile[64][65];
  int n0 = blockIdx.x * 64, k0 = blockIdx.y * 64;
  int tid = threadIdx.x;
  for (int i = tid; i < 4096; i += 256) {
    int r = i >> 6, c = i & 63;            // r = k-local, c = n-local
    tile[r][c] = W[(k0 + r) * N + n0 + c];
  }
  __syncthreads();
  for (int i = tid; i < 1024; i += 256) {
    int r = i >> 4, c4 = (i & 15) * 4;     // r = n-local, c4 = k-local
    ushort4 o;
    o.x = f2bf(tile[c4 + 0][r]); o.y = f2bf(tile[c4 + 1][r]);
    o.z = f2bf(tile[c4 + 2][r]); o.w = f2bf(tile[c4 + 3][r]);
    *reinterpret_cast<ushort4*>(&WT[(n0 + r) * 1024 + k0 + c4]) = o;
  }
}

// ---------------- bf16 MFMA GEMM: C[M][ldc] = A[M][1024] x BT[N][1024]^T ----
// 128x128 tile, 4 waves (2x2), BK=64. act=1: elu+1 epilogue.
#define LDK 72

__global__ __launch_bounds__(256) void mm_bf16(const unsigned short* __restrict__ A,
    const unsigned short* __restrict__ BT, float* __restrict__ C, int ldc, int act)
{
  __shared__ unsigned short As[128 * LDK];
  __shared__ unsigned short Bs[128 * LDK];
  int tid = threadIdx.x;
  int m0 = blockIdx.y * 128, n0 = blockIdx.x * 128;
  int wid = tid >> 6, lane = tid & 63;
  int wr = wid >> 1, wc = wid & 1;
  int lr = lane & 15, lg = lane >> 4;

  f32x4 acc[4][4];
#pragma unroll
  for (int m = 0; m < 4; ++m)
#pragma unroll
    for (int n = 0; n < 4; ++n)
#pragma unroll
      for (int r = 0; r < 4; ++r) acc[m][n][r] = 0.f;

  for (int kt = 0; kt < 16; ++kt) {
    int k0 = kt * 64;
#pragma unroll
    for (int p = 0; p < 4; ++p) {
      int c = p * 256 + tid;
      int row = c >> 3, k8 = c & 7;
      u16x8 va = *reinterpret_cast<const u16x8*>(A + (m0 + row) * 1024 + k0 + k8 * 8);
      *reinterpret_cast<u16x8*>(&As[row * LDK + k8 * 8]) = va;
      u16x8 vb = *reinterpret_cast<const u16x8*>(BT + (n0 + row) * 1024 + k0 + k8 * 8);
      *reinterpret_cast<u16x8*>(&Bs[row * LDK + k8 * 8]) = vb;
    }
    __syncthreads();
#pragma unroll
    for (int kk = 0; kk < 2; ++kk) {
      bf16x8 af[4], bfr[4];
#pragma unroll
      for (int m = 0; m < 4; ++m)
        af[m] = *reinterpret_cast<const bf16x8*>(&As[(wr * 64 + m * 16 + lr) * LDK + kk * 32 + lg * 8]);
#pragma unroll
      for (int n = 0; n < 4; ++n)
        bfr[n] = *reinterpret_cast<const bf16x8*>(&Bs[(wc * 64 + n * 16 + lr) * LDK + kk * 32 + lg * 8]);
#pragma unroll
      for (int m = 0; m < 4; ++m)
#pragma unroll
        for (int n = 0; n < 4; ++n)
          acc[m][n] = __builtin_amdgcn_mfma_f32_16x16x32_bf16(af[m], bfr[n], acc[m][n], 0, 0, 0);
    }
    __syncthreads();
  }
#pragma unroll
  for (int m = 0; m < 4; ++m)
#pragma unroll
    for (int n = 0; n < 4; ++n)
#pragma unroll
      for (int r = 0; r < 4; ++r) {
        float v = acc[m][n][r];
        if (act) v = v > 0.f ? v + 1.f : expf(v);
        C[(m0 + wr * 64 + m * 16 + lg * 4 + r) * ldc + n0 + wc * 64 + n * 16 + lr] = v;
      }
}

// fused QKV projections (z = q/k/v)
__global__ __launch_bounds__(256) void proj_bf16(const unsigned short* __restrict__ A,
    const unsigned short* __restrict__ WqT, const unsigned short* __restrict__ WkT,
    const unsigned short* __restrict__ WvT,
    float* __restrict__ Oq, float* __restrict__ Ok, float* __restrict__ Ov)
{
  int z = blockIdx.z;
  const unsigned short* BT = (z == 0) ? WqT : (z == 1) ? WkT : WvT;
  float* C = (z == 0) ? Oq : (z == 1) ? Ok : Ov;

  __shared__ unsigned short As[128 * LDK];
  __shared__ unsigned short Bs[128 * LDK];
  int tid = threadIdx.x;
  int m0 = blockIdx.y * 128, n0 = blockIdx.x * 128;
  int wid = tid >> 6, lane = tid & 63;
  int wr = wid >> 1, wc = wid & 1;
  int lr = lane & 15, lg = lane >> 4;
  int act = (z < 2) ? 1 : 0;

  f32x4 acc[4][4];
#pragma unroll
  for (int m = 0; m < 4; ++m)
#pragma unroll
    for (int n = 0; n < 4; ++n)
#pragma unroll
      for (int r = 0; r < 4; ++r) acc[m][n][r] = 0.f;

  for (int kt = 0; kt < 16; ++kt) {
    int k0 = kt * 64;
#pragma unroll
    for (int p = 0; p < 4; ++p) {
      int c = p * 256 + tid;
      int row = c >> 3, k8 = c & 7;
      u16x8 va = *reinterpret_cast<const u16x8*>(A + (m0 + row) * 1024 + k0 + k8 * 8);
      *reinterpret_cast<u16x8*>(&As[row * LDK + k8 * 8]) = va;
      u16x8 vb = *reinterpret_cast<const u16x8*>(BT + (n0 + row) * 1024 + k0 + k8 * 8);
      *reinterpret_cast<u16x8*>(&Bs[row * LDK + k8 * 8]) = vb;
    }
    __syncthreads();
#pragma unroll
    for (int kk = 0; kk < 2; ++kk) {
      bf16x8 af[4], bfr[4];
#pragma unroll
      for (int m = 0; m < 4; ++m)
        af[m] = *reinterpret_cast<const bf16x8*>(&As[(wr * 64 + m * 16 + lr) * LDK + kk * 32 + lg * 8]);
#pragma unroll
      for (int n = 0; n < 4; ++n)
        bfr[n] = *reinterpret_cast<const bf16x8*>(&Bs[(wc * 64 + n * 16 + lr) * LDK + kk * 32 + lg * 8]);
#pragma unroll
      for (int m = 0; m < 4; ++m)
#pragma unroll
        for (int n = 0; n < 4; ++n)
          acc[m][n] = __builtin_amdgcn_mfma_f32_16x16x32_bf16(af[m], bfr[n], acc[m][n], 0, 0, 0);
    }
    __syncthreads();
  }
#pragma unroll
  for (int m = 0; m < 4; ++m)
#pragma unroll
    for (int n = 0; n < 4; ++n)
#pragma unroll
      for (int r = 0; r < 4; ++r) {
        float v = acc[m][n][r];
        if (act) v = v > 0.f ? v + 1.f : expf(v);
        C[(m0 + wr * 64 + m * 16 + lg * 4 + r) * 1024 + n0 + wc * 64 + n * 16 + lr] = v;
      }
}

// ---------------- eg stage 2: relu(H1+b1)@w2 + b2 -> sigmoid ----------------
// one wave per row s; lane handles 4 of 256 cols.
__global__ __launch_bounds__(256) void eg_fin(const float* __restrict__ H1,
    const float* __restrict__ B1, const float* __restrict__ W2,
    const float* __restrict__ B2, float* __restrict__ EP)
{
  int wid = threadIdx.x >> 6, lane = threadIdx.x & 63;
  int s = blockIdx.x * 4 + wid;
  float4 h = *reinterpret_cast<const float4*>(H1 + s * 256 + lane * 4);
  float4 b = *reinterpret_cast<const float4*>(B1 + lane * 4);
  float4 w = *reinterpret_cast<const float4*>(W2 + lane * 4);
  float v = fmaxf(h.x + b.x, 0.f) * w.x + fmaxf(h.y + b.y, 0.f) * w.y
          + fmaxf(h.z + b.z, 0.f) * w.z + fmaxf(h.w + b.w, 0.f) * w.w;
  v = wave_allsum(v);
  if (lane == 0) EP[s] = 1.f / (1.f + expf(-(v + B2[0])));
}

// ---------------- K2: coarse retrieval + relevances ------------------------
__global__ __launch_bounds__(256) void coarse_kernel(const float* __restrict__ SQ,
    const float* __restrict__ MC, const float* __restrict__ ZC, const float* __restrict__ FN,
    float* __restrict__ CO, float* __restrict__ RELS, float* __restrict__ PARTS)
{
  int h = blockIdx.x, st = blockIdx.y;
  int tid = threadIdx.x;
  int s0 = st * 64;
  __shared__ __align__(16) float Mc[64][68];
  __shared__ __align__(16) float sqT[64][68];
  __shared__ float zf[5][64];
  __shared__ float relb[5][64];

  for (int idx = tid; idx < 4096; idx += 256) {
    int r = idx >> 6, d = idx & 63;
    Mc[r][d] = MC[h * 4096 + idx];
    sqT[d][r] = SQ[(s0 + r) * 1024 + h * 64 + d];
  }
  for (int idx = tid; idx < 320; idx += 256) {
    int w = idx >> 6, d = idx & 63;
    zf[w][d] = (w == 0) ? ZC[h * 64 + d] : FN[(w - 1) * 1024 + h * 64 + d];
  }
  __syncthreads();

  int tx = tid & 15, sy = tid >> 4;
  float acc[4][4] = {{0.f}};
  for (int dp = 0; dp < 64; ++dp) {
    float4 qv = *reinterpret_cast<const float4*>(&sqT[dp][sy * 4]);
    float4 mv = *reinterpret_cast<const float4*>(&Mc[dp][tx * 4]);
    float qa[4] = {qv.x, qv.y, qv.z, qv.w};
    float mb[4] = {mv.x, mv.y, mv.z, mv.w};
#pragma unroll
    for (int i = 0; i < 4; ++i)
#pragma unroll
      for (int j = 0; j < 4; ++j) acc[i][j] += qa[i] * mb[j];
  }
  {
    int s = tid & 63, wh = tid >> 6;
    float r = 0.f;
    for (int dp = 0; dp < 64; ++dp) r += sqT[dp][s] * zf[wh][dp];
    relb[wh][s] = r;
    if (wh == 0) {
      float r4 = 0.f;
      for (int dp = 0; dp < 64; ++dp) r4 += sqT[dp][s] * zf[4][dp];
      relb[4][s] = r4;
    }
  }
  __syncthreads();

#pragma unroll
  for (int i = 0; i < 4; ++i) {
    int s = sy * 4 + i;
    float rc = fmaxf(relb[0][s], EPSF);
    float4 o; o.x = acc[i][0] / rc; o.y = acc[i][1] / rc;
    o.z = acc[i][2] / rc; o.w = acc[i][3] / rc;
    *reinterpret_cast<float4*>(&CO[(s0 + s) * 1024 + h * 64 + tx * 4]) = o;
  }
  if (tid < 64) {
#pragma unroll
    for (int f = 0; f < 4; ++f)
      RELS[f * 32768 + h * 2048 + s0 + tid] = relb[1 + f][tid];
#pragma unroll
    for (int f = 0; f < 4; ++f) {
      float v = wave_allsum(relb[1 + f][tid]);
      if (tid == 0) PARTS[f * 512 + h * 32 + st] = v;
    }
  }
}

// ---------------- K4: bank softmax weights ----------------------------------
__global__ void weights_kernel(const float* __restrict__ P, float* __restrict__ W)
{
  int h = threadIdx.x;
  if (h >= 16) return;
  float r[4];
#pragma unroll
  for (int f = 0; f < 4; ++f) {
    float s = 0.f;
    for (int t = 0; t < 32; ++t) s += P[f * 512 + h * 32 + t];
    r[f] = s * (1.f / 2048.f);
  }
  float m = fmaxf(fmaxf(r[0], r[1]), fmaxf(r[2], r[3]));
  float e0 = expf(r[0] - m), e1 = expf(r[1] - m), e2 = expf(r[2] - m), e3 = expf(r[3] - m);
  float inv = 1.f / (e0 + e1 + e2 + e3);
  W[0 * 16 + h] = e0 * inv; W[1 * 16 + h] = e1 * inv;
  W[2 * 16 + h] = e2 * inv; W[3 * 16 + h] = e3 * inv;
}

// ---------------- K5: fine retrieval + memory combine -----------------------
__global__ __launch_bounds__(256) void fine_combine_kernel(const float* __restrict__ SQ,
    const float* __restrict__ FM, const float* __restrict__ RELS, const float* __restrict__ WT,
    const float* __restrict__ EP, const float* __restrict__ CO, float* __restrict__ MO)
{
  int h = blockIdx.x, st = blockIdx.y;
  int tid = threadIdx.x, d = tid & 63, g = tid >> 6;
  __shared__ float sqr[32][64];
  __shared__ float w4[4];
  if (tid < 4) w4[tid] = WT[tid * 16 + h];
  __syncthreads();

  for (int sb = 0; sb < 128; sb += 32) {
    int s0 = st * 128 + sb;
#pragma unroll
    for (int r = 0; r < 8; ++r)
      sqr[g * 8 + r][d] = SQ[(s0 + g * 8 + r) * 1024 + h * 64 + d];
    __syncthreads();

    float acc[4][8];
#pragma unroll
    for (int f = 0; f < 4; ++f)
#pragma unroll
      for (int r = 0; r < 8; ++r) acc[f][r] = 0.f;

    for (int dp = 0; dp < 64; ++dp) {
      float m0 = FM[           h * 4096 + dp * 64 + d];
      float m1 = FM[ 65536 +   h * 4096 + dp * 64 + d];
      float m2 = FM[131072 +   h * 4096 + dp * 64 + d];
      float m3 = FM[196608 +   h * 4096 + dp * 64 + d];
#pragma unroll
      for (int r = 0; r < 8; ++r) {
        float qv = sqr[g * 8 + r][dp];
        acc[0][r] += m0 * qv; acc[1][r] += m1 * qv;
        acc[2][r] += m2 * qv; acc[3][r] += m3 * qv;
      }
    }
#pragma unroll
    for (int r = 0; r < 8; ++r) {
      int s = s0 + g * 8 + r;
      float fine = 0.f;
#pragma unroll
      for (int f = 0; f < 4; ++f) {
        float rf = fmaxf(RELS[f * 32768 + h * 2048 + s], EPSF);
        fine += w4[f] * acc[f][r] / rf;
      }
      float e = EP[s];
      float cv = CO[s * 1024 + h * 64 + d];
      MO[s * 1024 + h * 64 + d] = e * fine + (1.f - e) * cv;
    }
    __syncthreads();
  }
}

// ---------------- K6: per-chunk KV state sums -------------------------------
__global__ __launch_bounds__(256) void chunk_state_kernel(const float* __restrict__ SK,
    const float* __restrict__ V, float* __restrict__ ST)
{
  int h = blockIdx.x, c = blockIdx.y, tid = threadIdx.x;
  __shared__ __align__(16) float sk[64][68];
  __shared__ __align__(16) float vv[64][68];
  for (int idx = tid; idx < 4096; idx += 256) {
    int s = idx >> 6, d = idx & 63;
    sk[s][d] = SK[(c * 64 + s) * 1024 + h * 64 + d];
    vv[s][d] = V [(c * 64 + s) * 1024 + h * 64 + d];
  }
  __syncthreads();
  int tx = tid & 15, dy = tid >> 4;
  float acc[4][4] = {{0.f}};
  for (int s = 0; s < 64; ++s) {
    float4 kd = *reinterpret_cast<const float4*>(&sk[s][dy * 4]);
    float4 ve = *reinterpret_cast<const float4*>(&vv[s][tx * 4]);
    float ka[4] = {kd.x, kd.y, kd.z, kd.w};
    float vb[4] = {ve.x, ve.y, ve.z, ve.w};
#pragma unroll
    for (int i = 0; i < 4; ++i)
#pragma unroll
      for (int j = 0; j < 4; ++j) acc[i][j] += ka[i] * vb[j];
  }
  float* base = ST + (h * 32 + c) * 4160;
#pragma unroll
  for (int i = 0; i < 4; ++i) {
    float4 o; o.x = acc[i][0]; o.y = acc[i][1]; o.z = acc[i][2]; o.w = acc[i][3];
    *reinterpret_cast<float4*>(&base[(dy * 4 + i) * 64 + tx * 4]) = o;
  }
  if (tid < 64) {
    float ks = 0.f;
    for (int s = 0; s < 64; ++s) ks += sk[s][tid];
    base[4096 + tid] = ks;
  }
}

// ---------------- K7: exclusive prefix over chunks (in place) ---------------
__global__ __launch_bounds__(256) void scan_kernel(float* __restrict__ ST)
{
  int h = blockIdx.x, tid = threadIdx.x;
  for (int idx = tid; idx < 4160; idx += 256) {
    float run = 0.f;
    for (int c = 0; c < 32; ++c) {
      float* p = ST + (h * 32 + c) * 4160 + idx;
      float t = *p; *p = run; run += t;
    }
  }
}

// ---------------- K8: causal linear attention within chunk ------------------
__global__ __launch_bounds__(256) void local_attn_kernel(const float* __restrict__ SQ,
    const float* __restrict__ SK, const float* __restrict__ V,
    const float* __restrict__ ST, float* __restrict__ OUT)
{
  int h = blockIdx.x, c = blockIdx.y, tid = threadIdx.x;
  __shared__ __align__(16) float sqT[64][68];
  __shared__ __align__(16) float skT[64][68];
  __shared__ __align__(16) float buf3[64][68];
  __shared__ float kprev[64];
  __shared__ float deni[64];
  const float* st = ST + (h * 32 + c) * 4160;

  for (int idx = tid; idx < 4096; idx += 256) {
    int r = idx >> 6, d = idx & 63;
    sqT[d][r] = SQ[(c * 64 + r) * 1024 + h * 64 + d];
    skT[d][r] = SK[(c * 64 + r) * 1024 + h * 64 + d];
    buf3[r][d] = st[idx];
  }
  if (tid < 64) kprev[tid] = st[4096 + tid];
  __syncthreads();

  int tx = tid & 15, sy = tid >> 4;
  float accn[4][4] = {{0.f}};
  for (int d = 0; d < 64; ++d) {
    float4 qv = *reinterpret_cast<const float4*>(&sqT[d][sy * 4]);
    float4 kv = *reinterpret_cast<const float4*>(&buf3[d][tx * 4]);
    float qa[4] = {qv.x, qv.y, qv.z, qv.w};
    float kb[4] = {kv.x, kv.y, kv.z, kv.w};
#pragma unroll
    for (int i = 0; i < 4; ++i)
#pragma unroll
      for (int j = 0; j < 4; ++j) accn[i][j] += qa[i] * kb[j];
  }
  if (tid < 64) {
    float dv = 0.f;
    for (int d = 0; d < 64; ++d) dv += sqT[d][tid] * kprev[d];
    deni[tid] = dv;
  }
  float sc[4][4] = {{0.f}};
  for (int d = 0; d < 64; ++d) {
    float4 qv = *reinterpret_cast<const float4*>(&sqT[d][sy * 4]);
    float4 kt = *reinterpret_cast<const float4*>(&skT[d][tx * 4]);
    float qa[4] = {qv.x, qv.y, qv.z, qv.w};
    float kb[4] = {kt.x, kt.y, kt.z, kt.w};
#pragma unroll
    for (int i = 0; i < 4; ++i)
#pragma unroll
      for (int j = 0; j < 4; ++j) sc[i][j] += qa[i] * kb[j];
  }
  __syncthreads();
#pragma unroll
  for (int i = 0; i < 4; ++i) {
    int s = sy * 4 + i;
#pragma unroll
    for (int j = 0; j < 4; ++j) {
      int t = tx * 4 + j;
      buf3[s][t] = (t <= s) ? sc[i][j] : 0.f;
    }
  }
  __syncthreads();
  for (int idx = tid; idx < 4096; idx += 256) {
    int r = idx >> 6, d = idx & 63;
    skT[r][d] = V[(c * 64 + r) * 1024 + h * 64 + d];
  }
  __syncthreads();
  for (int i = 0; i < 4; ++i) {
    int s = sy * 4 + i;
    float num[4] = {accn[i][0], accn[i][1], accn[i][2], accn[i][3]};
    float den = deni[s];
    for (int tb = 0; tb <= sy; ++tb) {
      float4 srow = *reinterpret_cast<const float4*>(&buf3[s][tb * 4]);
      float sv[4] = {srow.x, srow.y, srow.z, srow.w};
#pragma unroll
      for (int tt = 0; tt < 4; ++tt) {
        float4 vr = *reinterpret_cast<const float4*>(&skT[tb * 4 + tt][tx * 4]);
        num[0] += sv[tt] * vr.x; num[1] += sv[tt] * vr.y;
        num[2] += sv[tt] * vr.z; num[3] += sv[tt] * vr.w;
        den += sv[tt];
      }
    }
    den = fmaxf(den, EPSF);
    float4 o; o.x = num[0] / den; o.y = num[1] / den; o.z = num[2] / den; o.w = num[3] / den;
    *reinterpret_cast<float4*>(&OUT[(c * 64 + s) * 1024 + h * 64 + tx * 4]) = o;
  }
}

// ---------------- K9: gate combine ------------------------------------------
__global__ __launch_bounds__(256) void combine_kernel(const float* __restrict__ MO,
    const float* __restrict__ LO, const float* __restrict__ MG, float* __restrict__ CB)
{
  int idx = blockIdx.x * 256 + threadIdx.x;
  int hh = (idx >> 6) & 15;
  float g = 1.f / (1.f + expf(-MG[hh]));
  CB[idx] = g * MO[idx] + (1.f - g) * LO[idx];
}

// ---------------------------------------------------------------------------
extern "C" void kernel_launch(void* const* d_in, const int* in_sizes, int n_in,
                              void* d_out, int out_size, void* d_ws, size_t ws_size,
                              hipStream_t stream)
{
  const float* hs   = (const float*)d_in[0];
  const float* wq   = (const float*)d_in[1];
  const float* wk   = (const float*)d_in[2];
  const float* wv   = (const float*)d_in[3];
  const float* wo   = (const float*)d_in[4];
  const float* mg   = (const float*)d_in[5];
  const float* egw1 = (const float*)d_in[6];
  const float* egb1 = (const float*)d_in[7];
  const float* egw2 = (const float*)d_in[8];
  const float* egb2 = (const float*)d_in[9];
  const float* fm   = (const float*)d_in[10];
  const float* fn   = (const float*)d_in[11];
  float* out = (float*)d_out;

  float* ws     = (float*)d_ws;
  float* sq     = ws;                   // sigma_q        [2048][1024] f32
  float* sk     = sq + 2097152;         // sigma_k
  float* vv     = sk + 2097152;         // v
  float* co     = vv + 2097152;         // output_coarse
  float* mo     = co + 2097152;         // memory_output
  float* lo     = mo + 2097152;         // local_output
  float* mc     = lo + 2097152;         // M_coarse [16][64][64]
  float* zc     = mc + 65536;           // z_coarse [16][64]
  float* rels   = zc + 1024;            // rels [4][16][2048]
  float* parts  = rels + 131072;        // partial sums [4][16][32]
  float* wts    = parts + 2048;         // weights [4][16]
  float* ep     = wts + 64;             // expansion prob [2048]
  float* states = ep + 2048;            // chunk states [16][32][4160]
  float* cb     = sk;                   // combined aliases sigma_k (dead by then)

  // bf16 / scratch aliases (all stream-order safe):
  unsigned short* hsb = (unsigned short*)co;            // hs bf16; co written later
  unsigned short* wqT = (unsigned short*)mo;            // 3 x [1024][1024] bf16
  unsigned short* wkT = wqT + 1048576;
  unsigned short* wvT = wkT + 1048576;
  float*          h1  = mo + 1572864;                   // eg H1 [2048][256] f32 (rest of mo)
  unsigned short* cob = (unsigned short*)lo;            // CO bf16; lo written by local_attn later
  unsigned short* woT = (unsigned short*)(lo + 1048576);// wo bf16 (cast after combine)
  unsigned short* w1T = (unsigned short*)states;        // eg_w1T bf16 [256][1024]; states written later
  unsigned short* cbb = (unsigned short*)sq;            // combined bf16 (cast after local_attn)

  k0_summem<<<256, 256, 0, stream>>>(fm, fn, mc, zc);
  cast_bf16_k<<<2048, 256, 0, stream>>>(hs, hsb);
  cast_transpose_k<<<dim3(16, 16), 256, 0, stream>>>(wq, wqT, 1024);
  cast_transpose_k<<<dim3(16, 16), 256, 0, stream>>>(wk, wkT, 1024);
  cast_transpose_k<<<dim3(16, 16), 256, 0, stream>>>(wv, wvT, 1024);
  cast_transpose_k<<<dim3(4, 16), 256, 0, stream>>>(egw1, w1T, 256);
  proj_bf16<<<dim3(8, 16, 3), 256, 0, stream>>>(hsb, wqT, wkT, wvT, sq, sk, vv);
  coarse_kernel<<<dim3(16, 32), 256, 0, stream>>>(sq, mc, zc, fn, co, rels, parts);
  cast_bf16_k<<<2048, 256, 0, stream>>>(co, cob);
  mm_bf16<<<dim3(2, 16), 256, 0, stream>>>(cob, w1T, h1, 256, 0);          // eg stage 1
  eg_fin<<<512, 256, 0, stream>>>(h1, egb1, egw2, egb2, ep);               // eg stage 2
  weights_kernel<<<1, 64, 0, stream>>>(parts, wts);
  fine_combine_kernel<<<dim3(16, 16), 256, 0, stream>>>(sq, fm, rels, wts, ep, co, mo);
  chunk_state_kernel<<<dim3(16, 32), 256, 0, stream>>>(sk, vv, states);
  scan_kernel<<<16, 256, 0, stream>>>(states);
  local_attn_kernel<<<dim3(16, 32), 256, 0, stream>>>(sq, sk, vv, states, lo);
  combine_kernel<<<8192, 256, 0, stream>>>(mo, lo, mg, cb);
  cast_bf16_k<<<2048, 256, 0, stream>>>(cb, cbb);
  cast_transpose_k<<<dim3(16, 16), 256, 0, stream>>>(wo, woT, 1024);
  mm_bf16<<<dim3(8, 16), 256, 0, stream>>>(cbb, woT, out, 1024, 0);
}

// Round 8
// 199.218 us; speedup vs baseline: 2.2586x; 1.2817x over previous
//
#include <hip/hip_runtime.h>
#include <cmath>

#define EPSF 1e-6f

// ---------------------------------------------------------------------------
// Shapes: B=1, S=2048, H=16, D=64, hid=1024
// R6: QKV+out-proj bf16 MFMA. R7: eg stage1 MFMA. R8: fine retrieval MFMA
// (was 53.6us latency-bound fp32 @ 1 block/CU) + scan re-grid (512-deep
// dependent chain -> 32-deep).
// ---------------------------------------------------------------------------

typedef __attribute__((ext_vector_type(8))) short bf16x8;
typedef __attribute__((ext_vector_type(4))) float f32x4;
typedef __attribute__((ext_vector_type(8))) unsigned short u16x8;

__device__ __forceinline__ float wave_allsum(float v) {
#pragma unroll
  for (int off = 32; off > 0; off >>= 1) v += __shfl_xor(v, off, 64);
  return v;
}

__device__ __forceinline__ unsigned short f2bf(float f) {  // RNE f32->bf16
  unsigned int u = __float_as_uint(f);
  unsigned int r = (u + 0x7fffu + ((u >> 16) & 1u)) >> 16;
  return (unsigned short)r;
}

// ---------------- K0: coarse memory = sum of fine banks --------------------
__global__ __launch_bounds__(256) void k0_summem(const float* __restrict__ FM,
    const float* __restrict__ FN, float* __restrict__ MC, float* __restrict__ ZC)
{
  int idx = blockIdx.x * 256 + threadIdx.x;
  if (idx < 65536)
    MC[idx] = FM[idx] + FM[65536 + idx] + FM[131072 + idx] + FM[196608 + idx];
  if (idx < 1024)
    ZC[idx] = FN[idx] + FN[1024 + idx] + FN[2048 + idx] + FN[3072 + idx];
}

// ---------------- cast kernels ---------------------------------------------
__global__ __launch_bounds__(256) void cast_bf16_k(const float* __restrict__ X,
    unsigned short* __restrict__ Y)
{
  int i = blockIdx.x * 256 + threadIdx.x;
  float4 v = *reinterpret_cast<const float4*>(X + i * 4);
  ushort4 o; o.x = f2bf(v.x); o.y = f2bf(v.y); o.z = f2bf(v.z); o.w = f2bf(v.w);
  *reinterpret_cast<ushort4*>(Y + i * 4) = o;
}

// W [1024][N] f32 row-major -> WT [N][1024] bf16. grid (N/64, 16).
__global__ __launch_bounds__(256) void cast_transpose_k(const float* __restrict__ W,
    unsigned short* __restrict__ WT, int N)
{
  __shared__ float tile[64][65];
  int n0 = blockIdx.x * 64, k0 = blockIdx.y * 64;
  int tid = threadIdx.x;
  for (int i = tid; i < 4096; i += 256) {
    int r = i >> 6, c = i & 63;
    tile[r][c] = W[(k0 + r) * N + n0 + c];
  }
  __syncthreads();
  for (int i = tid; i < 1024; i += 256) {
    int r = i >> 4, c4 = (i & 15) * 4;
    ushort4 o;
    o.x = f2bf(tile[c4 + 0][r]); o.y = f2bf(tile[c4 + 1][r]);
    o.z = f2bf(tile[c4 + 2][r]); o.w = f2bf(tile[c4 + 3][r]);
    *reinterpret_cast<ushort4*>(&WT[(n0 + r) * 1024 + k0 + c4]) = o;
  }
}

// FM f32 [64 mats][64 dp][64 e] -> FMT bf16 [64 mats][e][dp] (per-matrix T)
__global__ __launch_bounds__(256) void fm_cast_t(const float* __restrict__ FM,
    unsigned short* __restrict__ FMT)
{
  __shared__ float tile[64][65];
  int b = blockIdx.x, tid = threadIdx.x;
  const float* src = FM + b * 4096;
  for (int i = tid; i < 4096; i += 256) tile[i >> 6][i & 63] = src[i];
  __syncthreads();
  unsigned short* dst = FMT + b * 4096;
  for (int i = tid; i < 4096; i += 256) {
    int e = i >> 6, dp = i & 63;
    dst[e * 64 + dp] = f2bf(tile[dp][e]);
  }
}

// ---------------- bf16 MFMA GEMM: C[M][ldc] = A[M][1024] x BT[N][1024]^T ----
#define LDK 72

__global__ __launch_bounds__(256) void mm_bf16(const unsigned short* __restrict__ A,
    const unsigned short* __restrict__ BT, float* __restrict__ C, int ldc, int act)
{
  __shared__ unsigned short As[128 * LDK];
  __shared__ unsigned short Bs[128 * LDK];
  int tid = threadIdx.x;
  int m0 = blockIdx.y * 128, n0 = blockIdx.x * 128;
  int wid = tid >> 6, lane = tid & 63;
  int wr = wid >> 1, wc = wid & 1;
  int lr = lane & 15, lg = lane >> 4;

  f32x4 acc[4][4];
#pragma unroll
  for (int m = 0; m < 4; ++m)
#pragma unroll
    for (int n = 0; n < 4; ++n)
#pragma unroll
      for (int r = 0; r < 4; ++r) acc[m][n][r] = 0.f;

  for (int kt = 0; kt < 16; ++kt) {
    int k0 = kt * 64;
#pragma unroll
    for (int p = 0; p < 4; ++p) {
      int c = p * 256 + tid;
      int row = c >> 3, k8 = c & 7;
      u16x8 va = *reinterpret_cast<const u16x8*>(A + (m0 + row) * 1024 + k0 + k8 * 8);
      *reinterpret_cast<u16x8*>(&As[row * LDK + k8 * 8]) = va;
      u16x8 vb = *reinterpret_cast<const u16x8*>(BT + (n0 + row) * 1024 + k0 + k8 * 8);
      *reinterpret_cast<u16x8*>(&Bs[row * LDK + k8 * 8]) = vb;
    }
    __syncthreads();
#pragma unroll
    for (int kk = 0; kk < 2; ++kk) {
      bf16x8 af[4], bfr[4];
#pragma unroll
      for (int m = 0; m < 4; ++m)
        af[m] = *reinterpret_cast<const bf16x8*>(&As[(wr * 64 + m * 16 + lr) * LDK + kk * 32 + lg * 8]);
#pragma unroll
      for (int n = 0; n < 4; ++n)
        bfr[n] = *reinterpret_cast<const bf16x8*>(&Bs[(wc * 64 + n * 16 + lr) * LDK + kk * 32 + lg * 8]);
#pragma unroll
      for (int m = 0; m < 4; ++m)
#pragma unroll
        for (int n = 0; n < 4; ++n)
          acc[m][n] = __builtin_amdgcn_mfma_f32_16x16x32_bf16(af[m], bfr[n], acc[m][n], 0, 0, 0);
    }
    __syncthreads();
  }
#pragma unroll
  for (int m = 0; m < 4; ++m)
#pragma unroll
    for (int n = 0; n < 4; ++n)
#pragma unroll
      for (int r = 0; r < 4; ++r) {
        float v = acc[m][n][r];
        if (act) v = v > 0.f ? v + 1.f : expf(v);
        C[(m0 + wr * 64 + m * 16 + lg * 4 + r) * ldc + n0 + wc * 64 + n * 16 + lr] = v;
      }
}

// fused QKV projections (z = q/k/v)
__global__ __launch_bounds__(256) void proj_bf16(const unsigned short* __restrict__ A,
    const unsigned short* __restrict__ WqT, const unsigned short* __restrict__ WkT,
    const unsigned short* __restrict__ WvT,
    float* __restrict__ Oq, float* __restrict__ Ok, float* __restrict__ Ov)
{
  int z = blockIdx.z;
  const unsigned short* BT = (z == 0) ? WqT : (z == 1) ? WkT : WvT;
  float* C = (z == 0) ? Oq : (z == 1) ? Ok : Ov;

  __shared__ unsigned short As[128 * LDK];
  __shared__ unsigned short Bs[128 * LDK];
  int tid = threadIdx.x;
  int m0 = blockIdx.y * 128, n0 = blockIdx.x * 128;
  int wid = tid >> 6, lane = tid & 63;
  int wr = wid >> 1, wc = wid & 1;
  int lr = lane & 15, lg = lane >> 4;
  int act = (z < 2) ? 1 : 0;

  f32x4 acc[4][4];
#pragma unroll
  for (int m = 0; m < 4; ++m)
#pragma unroll
    for (int n = 0; n < 4; ++n)
#pragma unroll
      for (int r = 0; r < 4; ++r) acc[m][n][r] = 0.f;

  for (int kt = 0; kt < 16; ++kt) {
    int k0 = kt * 64;
#pragma unroll
    for (int p = 0; p < 4; ++p) {
      int c = p * 256 + tid;
      int row = c >> 3, k8 = c & 7;
      u16x8 va = *reinterpret_cast<const u16x8*>(A + (m0 + row) * 1024 + k0 + k8 * 8);
      *reinterpret_cast<u16x8*>(&As[row * LDK + k8 * 8]) = va;
      u16x8 vb = *reinterpret_cast<const u16x8*>(BT + (n0 + row) * 1024 + k0 + k8 * 8);
      *reinterpret_cast<u16x8*>(&Bs[row * LDK + k8 * 8]) = vb;
    }
    __syncthreads();
#pragma unroll
    for (int kk = 0; kk < 2; ++kk) {
      bf16x8 af[4], bfr[4];
#pragma unroll
      for (int m = 0; m < 4; ++m)
        af[m] = *reinterpret_cast<const bf16x8*>(&As[(wr * 64 + m * 16 + lr) * LDK + kk * 32 + lg * 8]);
#pragma unroll
      for (int n = 0; n < 4; ++n)
        bfr[n] = *reinterpret_cast<const bf16x8*>(&Bs[(wc * 64 + n * 16 + lr) * LDK + kk * 32 + lg * 8]);
#pragma unroll
      for (int m = 0; m < 4; ++m)
#pragma unroll
        for (int n = 0; n < 4; ++n)
          acc[m][n] = __builtin_amdgcn_mfma_f32_16x16x32_bf16(af[m], bfr[n], acc[m][n], 0, 0, 0);
    }
    __syncthreads();
  }
#pragma unroll
  for (int m = 0; m < 4; ++m)
#pragma unroll
    for (int n = 0; n < 4; ++n)
#pragma unroll
      for (int r = 0; r < 4; ++r) {
        float v = acc[m][n][r];
        if (act) v = v > 0.f ? v + 1.f : expf(v);
        C[(m0 + wr * 64 + m * 16 + lg * 4 + r) * 1024 + n0 + wc * 64 + n * 16 + lr] = v;
      }
}

// ---------------- eg stage 2: relu(H1+b1)@w2 + b2 -> sigmoid ----------------
__global__ __launch_bounds__(256) void eg_fin(const float* __restrict__ H1,
    const float* __restrict__ B1, const float* __restrict__ W2,
    const float* __restrict__ B2, float* __restrict__ EP)
{
  int wid = threadIdx.x >> 6, lane = threadIdx.x & 63;
  int s = blockIdx.x * 4 + wid;
  float4 h = *reinterpret_cast<const float4*>(H1 + s * 256 + lane * 4);
  float4 b = *reinterpret_cast<const float4*>(B1 + lane * 4);
  float4 w = *reinterpret_cast<const float4*>(W2 + lane * 4);
  float v = fmaxf(h.x + b.x, 0.f) * w.x + fmaxf(h.y + b.y, 0.f) * w.y
          + fmaxf(h.z + b.z, 0.f) * w.z + fmaxf(h.w + b.w, 0.f) * w.w;
  v = wave_allsum(v);
  if (lane == 0) EP[s] = 1.f / (1.f + expf(-(v + B2[0])));
}

// ---------------- K2: coarse retrieval + relevances ------------------------
__global__ __launch_bounds__(256) void coarse_kernel(const float* __restrict__ SQ,
    const float* __restrict__ MC, const float* __restrict__ ZC, const float* __restrict__ FN,
    float* __restrict__ CO, float* __restrict__ RELS, float* __restrict__ PARTS)
{
  int h = blockIdx.x, st = blockIdx.y;
  int tid = threadIdx.x;
  int s0 = st * 64;
  __shared__ __align__(16) float Mc[64][68];
  __shared__ __align__(16) float sqT[64][68];
  __shared__ float zf[5][64];
  __shared__ float relb[5][64];

  for (int idx = tid; idx < 4096; idx += 256) {
    int r = idx >> 6, d = idx & 63;
    Mc[r][d] = MC[h * 4096 + idx];
    sqT[d][r] = SQ[(s0 + r) * 1024 + h * 64 + d];
  }
  for (int idx = tid; idx < 320; idx += 256) {
    int w = idx >> 6, d = idx & 63;
    zf[w][d] = (w == 0) ? ZC[h * 64 + d] : FN[(w - 1) * 1024 + h * 64 + d];
  }
  __syncthreads();

  int tx = tid & 15, sy = tid >> 4;
  float acc[4][4] = {{0.f}};
  for (int dp = 0; dp < 64; ++dp) {
    float4 qv = *reinterpret_cast<const float4*>(&sqT[dp][sy * 4]);
    float4 mv = *reinterpret_cast<const float4*>(&Mc[dp][tx * 4]);
    float qa[4] = {qv.x, qv.y, qv.z, qv.w};
    float mb[4] = {mv.x, mv.y, mv.z, mv.w};
#pragma unroll
    for (int i = 0; i < 4; ++i)
#pragma unroll
      for (int j = 0; j < 4; ++j) acc[i][j] += qa[i] * mb[j];
  }
  {
    int s = tid & 63, wh = tid >> 6;
    float r = 0.f;
    for (int dp = 0; dp < 64; ++dp) r += sqT[dp][s] * zf[wh][dp];
    relb[wh][s] = r;
    if (wh == 0) {
      float r4 = 0.f;
      for (int dp = 0; dp < 64; ++dp) r4 += sqT[dp][s] * zf[4][dp];
      relb[4][s] = r4;
    }
  }
  __syncthreads();

#pragma unroll
  for (int i = 0; i < 4; ++i) {
    int s = sy * 4 + i;
    float rc = fmaxf(relb[0][s], EPSF);
    float4 o; o.x = acc[i][0] / rc; o.y = acc[i][1] / rc;
    o.z = acc[i][2] / rc; o.w = acc[i][3] / rc;
    *reinterpret_cast<float4*>(&CO[(s0 + s) * 1024 + h * 64 + tx * 4]) = o;
  }
  if (tid < 64) {
#pragma unroll
    for (int f = 0; f < 4; ++f)
      RELS[f * 32768 + h * 2048 + s0 + tid] = relb[1 + f][tid];
#pragma unroll
    for (int f = 0; f < 4; ++f) {
      float v = wave_allsum(relb[1 + f][tid]);
      if (tid == 0) PARTS[f * 512 + h * 32 + st] = v;
    }
  }
}

// ---------------- K4: bank softmax weights ----------------------------------
__global__ void weights_kernel(const float* __restrict__ P, float* __restrict__ W)
{
  int h = threadIdx.x;
  if (h >= 16) return;
  float r[4];
#pragma unroll
  for (int f = 0; f < 4; ++f) {
    float s = 0.f;
    for (int t = 0; t < 32; ++t) s += P[f * 512 + h * 32 + t];
    r[f] = s * (1.f / 2048.f);
  }
  float m = fmaxf(fmaxf(r[0], r[1]), fmaxf(r[2], r[3]));
  float e0 = expf(r[0] - m), e1 = expf(r[1] - m), e2 = expf(r[2] - m), e3 = expf(r[3] - m);
  float inv = 1.f / (e0 + e1 + e2 + e3);
  W[0 * 16 + h] = e0 * inv; W[1 * 16 + h] = e1 * inv;
  W[2 * 16 + h] = e2 * inv; W[3 * 16 + h] = e3 * inv;
}

// ---------------- K5': fine retrieval + combine, bf16 MFMA ------------------
// grid (16 h, 16 st). Block: 128 rows. Wave w: rows [w*32, w*32+32).
// acc[f][m][n]: per-bank outputs combined in-register in the epilogue.
__global__ __launch_bounds__(256) void fine_mfma(const unsigned short* __restrict__ SQB,
    const unsigned short* __restrict__ FMT, const float* __restrict__ RELS,
    const float* __restrict__ WT, const float* __restrict__ EP,
    const float* __restrict__ CO, float* __restrict__ MO)
{
  int h = blockIdx.x, st = blockIdx.y;
  int tid = threadIdx.x;
  int w = tid >> 6, lane = tid & 63;
  int lr = lane & 15, lg = lane >> 4;
  int s0 = st * 128;

  __shared__ unsigned short A_lds[128 * LDK];      // sigma_q tile [row][k]
  __shared__ unsigned short B_lds[4 * 64 * LDK];   // 4 banks [e][dp]
  __shared__ float w4s[4];
  if (tid < 4) w4s[tid] = WT[tid * 16 + h];

#pragma unroll
  for (int p = 0; p < 4; ++p) {
    int c = p * 256 + tid;
    int row = c >> 3, k8 = c & 7;
    u16x8 v = *reinterpret_cast<const u16x8*>(SQB + (s0 + row) * 1024 + h * 64 + k8 * 8);
    *reinterpret_cast<u16x8*>(&A_lds[row * LDK + k8 * 8]) = v;
  }
#pragma unroll
  for (int p = 0; p < 8; ++p) {
    int c = p * 256 + tid;                 // 2048 chunks = 4 banks x 64 e x 8
    int f = c >> 9, rem = c & 511;
    int e = rem >> 3, k8 = rem & 7;
    u16x8 v = *reinterpret_cast<const u16x8*>(FMT + (f * 16 + h) * 4096 + e * 64 + k8 * 8);
    *reinterpret_cast<u16x8*>(&B_lds[(f * 64 + e) * LDK + k8 * 8]) = v;
  }
  __syncthreads();

  f32x4 acc[4][2][4];
#pragma unroll
  for (int f = 0; f < 4; ++f)
#pragma unroll
    for (int m = 0; m < 2; ++m)
#pragma unroll
      for (int n = 0; n < 4; ++n)
#pragma unroll
        for (int r = 0; r < 4; ++r) acc[f][m][n][r] = 0.f;

#pragma unroll
  for (int kk = 0; kk < 2; ++kk) {
    bf16x8 af[2];
#pragma unroll
    for (int m = 0; m < 2; ++m)
      af[m] = *reinterpret_cast<const bf16x8*>(&A_lds[(w * 32 + m * 16 + lr) * LDK + kk * 32 + lg * 8]);
#pragma unroll
    for (int f = 0; f < 4; ++f) {
      bf16x8 bf4[4];
#pragma unroll
      for (int n = 0; n < 4; ++n)
        bf4[n] = *reinterpret_cast<const bf16x8*>(&B_lds[(f * 64 + n * 16 + lr) * LDK + kk * 32 + lg * 8]);
#pragma unroll
      for (int m = 0; m < 2; ++m)
#pragma unroll
        for (int n = 0; n < 4; ++n)
          acc[f][m][n] = __builtin_amdgcn_mfma_f32_16x16x32_bf16(af[m], bf4[n], acc[f][m][n], 0, 0, 0);
    }
  }

#pragma unroll
  for (int m = 0; m < 2; ++m)
#pragma unroll
    for (int r = 0; r < 4; ++r) {
      int s = s0 + w * 32 + m * 16 + lg * 4 + r;
      float e = EP[s];
      float i0 = w4s[0] / fmaxf(RELS[0 * 32768 + h * 2048 + s], EPSF);
      float i1 = w4s[1] / fmaxf(RELS[1 * 32768 + h * 2048 + s], EPSF);
      float i2 = w4s[2] / fmaxf(RELS[2 * 32768 + h * 2048 + s], EPSF);
      float i3 = w4s[3] / fmaxf(RELS[3 * 32768 + h * 2048 + s], EPSF);
#pragma unroll
      for (int n = 0; n < 4; ++n) {
        int dg = h * 64 + n * 16 + lr;
        float fine = acc[0][m][n][r] * i0 + acc[1][m][n][r] * i1
                   + acc[2][m][n][r] * i2 + acc[3][m][n][r] * i3;
        float cv = CO[s * 1024 + dg];
        MO[s * 1024 + dg] = e * fine + (1.f - e) * cv;
      }
    }
}

// ---------------- K6: per-chunk KV state sums -------------------------------
__global__ __launch_bounds__(256) void chunk_state_kernel(const float* __restrict__ SK,
    const float* __restrict__ V, float* __restrict__ ST)
{
  int h = blockIdx.x, c = blockIdx.y, tid = threadIdx.x;
  __shared__ __align__(16) float sk[64][68];
  __shared__ __align__(16) float vv[64][68];
  for (int idx = tid; idx < 4096; idx += 256) {
    int s = idx >> 6, d = idx & 63;
    sk[s][d] = SK[(c * 64 + s) * 1024 + h * 64 + d];
    vv[s][d] = V [(c * 64 + s) * 1024 + h * 64 + d];
  }
  __syncthreads();
  int tx = tid & 15, dy = tid >> 4;
  float acc[4][4] = {{0.f}};
  for (int s = 0; s < 64; ++s) {
    float4 kd = *reinterpret_cast<const float4*>(&sk[s][dy * 4]);
    float4 ve = *reinterpret_cast<const float4*>(&vv[s][tx * 4]);
    float ka[4] = {kd.x, kd.y, kd.z, kd.w};
    float vb[4] = {ve.x, ve.y, ve.z, ve.w};
#pragma unroll
    for (int i = 0; i < 4; ++i)
#pragma unroll
      for (int j = 0; j < 4; ++j) acc[i][j] += ka[i] * vb[j];
  }
  float* base = ST + (h * 32 + c) * 4160;
#pragma unroll
  for (int i = 0; i < 4; ++i) {
    float4 o; o.x = acc[i][0]; o.y = acc[i][1]; o.z = acc[i][2]; o.w = acc[i][3];
    *reinterpret_cast<float4*>(&base[(dy * 4 + i) * 64 + tx * 4]) = o;
  }
  if (tid < 64) {
    float ks = 0.f;
    for (int s = 0; s < 64; ++s) ks += sk[s][tid];
    base[4096 + tid] = ks;
  }
}

// ---------------- K7: exclusive prefix over chunks (re-gridded) -------------
__global__ __launch_bounds__(256) void scan_kernel(float* __restrict__ ST)
{
  int gidx = blockIdx.x * 256 + threadIdx.x;   // 16 h x 4160 idx
  int h = gidx / 4160, idx = gidx - h * 4160;
  if (h >= 16) return;
  float run = 0.f;
#pragma unroll 4
  for (int c = 0; c < 32; ++c) {
    float* p = ST + (h * 32 + c) * 4160 + idx;
    float t = *p; *p = run; run += t;
  }
}

// ---------------- K8: causal linear attention within chunk ------------------
__global__ __launch_bounds__(256) void local_attn_kernel(const float* __restrict__ SQ,
    const float* __restrict__ SK, const float* __restrict__ V,
    const float* __restrict__ ST, float* __restrict__ OUT)
{
  int h = blockIdx.x, c = blockIdx.y, tid = threadIdx.x;
  __shared__ __align__(16) float sqT[64][68];
  __shared__ __align__(16) float skT[64][68];
  __shared__ __align__(16) float buf3[64][68];
  __shared__ float kprev[64];
  __shared__ float deni[64];
  const float* st = ST + (h * 32 + c) * 4160;

  for (int idx = tid; idx < 4096; idx += 256) {
    int r = idx >> 6, d = idx & 63;
    sqT[d][r] = SQ[(c * 64 + r) * 1024 + h * 64 + d];
    skT[d][r] = SK[(c * 64 + r) * 1024 + h * 64 + d];
    buf3[r][d] = st[idx];
  }
  if (tid < 64) kprev[tid] = st[4096 + tid];
  __syncthreads();

  int tx = tid & 15, sy = tid >> 4;
  float accn[4][4] = {{0.f}};
  for (int d = 0; d < 64; ++d) {
    float4 qv = *reinterpret_cast<const float4*>(&sqT[d][sy * 4]);
    float4 kv = *reinterpret_cast<const float4*>(&buf3[d][tx * 4]);
    float qa[4] = {qv.x, qv.y, qv.z, qv.w};
    float kb[4] = {kv.x, kv.y, kv.z, kv.w};
#pragma unroll
    for (int i = 0; i < 4; ++i)
#pragma unroll
      for (int j = 0; j < 4; ++j) accn[i][j] += qa[i] * kb[j];
  }
  if (tid < 64) {
    float dv = 0.f;
    for (int d = 0; d < 64; ++d) dv += sqT[d][tid] * kprev[d];
    deni[tid] = dv;
  }
  float sc[4][4] = {{0.f}};
  for (int d = 0; d < 64; ++d) {
    float4 qv = *reinterpret_cast<const float4*>(&sqT[d][sy * 4]);
    float4 kt = *reinterpret_cast<const float4*>(&skT[d][tx * 4]);
    float qa[4] = {qv.x, qv.y, qv.z, qv.w};
    float kb[4] = {kt.x, kt.y, kt.z, kt.w};
#pragma unroll
    for (int i = 0; i < 4; ++i)
#pragma unroll
      for (int j = 0; j < 4; ++j) sc[i][j] += qa[i] * kb[j];
  }
  __syncthreads();
#pragma unroll
  for (int i = 0; i < 4; ++i) {
    int s = sy * 4 + i;
#pragma unroll
    for (int j = 0; j < 4; ++j) {
      int t = tx * 4 + j;
      buf3[s][t] = (t <= s) ? sc[i][j] : 0.f;
    }
  }
  __syncthreads();
  for (int idx = tid; idx < 4096; idx += 256) {
    int r = idx >> 6, d = idx & 63;
    skT[r][d] = V[(c * 64 + r) * 1024 + h * 64 + d];
  }
  __syncthreads();
  for (int i = 0; i < 4; ++i) {
    int s = sy * 4 + i;
    float num[4] = {accn[i][0], accn[i][1], accn[i][2], accn[i][3]};
    float den = deni[s];
    for (int tb = 0; tb <= sy; ++tb) {
      float4 srow = *reinterpret_cast<const float4*>(&buf3[s][tb * 4]);
      float sv[4] = {srow.x, srow.y, srow.z, srow.w};
#pragma unroll
      for (int tt = 0; tt < 4; ++tt) {
        float4 vr = *reinterpret_cast<const float4*>(&skT[tb * 4 + tt][tx * 4]);
        num[0] += sv[tt] * vr.x; num[1] += sv[tt] * vr.y;
        num[2] += sv[tt] * vr.z; num[3] += sv[tt] * vr.w;
        den += sv[tt];
      }
    }
    den = fmaxf(den, EPSF);
    float4 o; o.x = num[0] / den; o.y = num[1] / den; o.z = num[2] / den; o.w = num[3] / den;
    *reinterpret_cast<float4*>(&OUT[(c * 64 + s) * 1024 + h * 64 + tx * 4]) = o;
  }
}

// ---------------- K9: gate combine ------------------------------------------
__global__ __launch_bounds__(256) void combine_kernel(const float* __restrict__ MO,
    const float* __restrict__ LO, const float* __restrict__ MG, float* __restrict__ CB)
{
  int idx = blockIdx.x * 256 + threadIdx.x;
  int hh = (idx >> 6) & 15;
  float g = 1.f / (1.f + expf(-MG[hh]));
  CB[idx] = g * MO[idx] + (1.f - g) * LO[idx];
}

// ---------------------------------------------------------------------------
extern "C" void kernel_launch(void* const* d_in, const int* in_sizes, int n_in,
                              void* d_out, int out_size, void* d_ws, size_t ws_size,
                              hipStream_t stream)
{
  const float* hs   = (const float*)d_in[0];
  const float* wq   = (const float*)d_in[1];
  const float* wk   = (const float*)d_in[2];
  const float* wv   = (const float*)d_in[3];
  const float* wo   = (const float*)d_in[4];
  const float* mg   = (const float*)d_in[5];
  const float* egw1 = (const float*)d_in[6];
  const float* egb1 = (const float*)d_in[7];
  const float* egw2 = (const float*)d_in[8];
  const float* egb2 = (const float*)d_in[9];
  const float* fm   = (const float*)d_in[10];
  const float* fn   = (const float*)d_in[11];
  float* out = (float*)d_out;

  float* ws     = (float*)d_ws;
  float* sq     = ws;                   // sigma_q        [2048][1024] f32
  float* sk     = sq + 2097152;         // sigma_k
  float* vv     = sk + 2097152;         // v
  float* co     = vv + 2097152;         // output_coarse
  float* mo     = co + 2097152;         // memory_output
  float* lo     = mo + 2097152;         // local_output
  float* mc     = lo + 2097152;         // M_coarse [16][64][64]
  float* zc     = mc + 65536;           // z_coarse [16][64]
  float* rels   = zc + 1024;            // rels [4][16][2048]
  float* parts  = rels + 131072;        // partial sums [4][16][32]
  float* wts    = parts + 2048;         // weights [4][16]
  float* ep     = wts + 64;             // expansion prob [2048]
  float* states = ep + 2048;            // chunk states [16][32][4160]
  float* cb     = sk;                   // combined aliases sigma_k

  // bf16 / scratch aliases (all stream-order safe):
  unsigned short* hsb = (unsigned short*)co;             // hs bf16; co written later
  unsigned short* wqT = (unsigned short*)mo;             // 3 x [1024][1024] bf16
  unsigned short* wkT = wqT + 1048576;
  unsigned short* wvT = wkT + 1048576;
  float*          h1  = mo + 1572864;                    // eg H1 [2048][256] f32
  unsigned short* cob = (unsigned short*)lo;             // CO bf16 [0..1048576 f)
  unsigned short* woT = (unsigned short*)(lo + 1048576); // wo bf16 [524288 f)
  unsigned short* fmbT= (unsigned short*)(lo + 1572864); // FM^T bf16 [131072 f); dead before local_attn writes lo
  unsigned short* w1T = (unsigned short*)states;         // eg_w1T bf16 [131072 f)
  unsigned short* sqb = (unsigned short*)(states + 131072); // sigma_q bf16 [1048576 f); dead before chunk_state writes states
  unsigned short* cbb = (unsigned short*)sq;             // combined bf16

  k0_summem<<<256, 256, 0, stream>>>(fm, fn, mc, zc);
  cast_bf16_k<<<2048, 256, 0, stream>>>(hs, hsb);
  cast_transpose_k<<<dim3(16, 16), 256, 0, stream>>>(wq, wqT, 1024);
  cast_transpose_k<<<dim3(16, 16), 256, 0, stream>>>(wk, wkT, 1024);
  cast_transpose_k<<<dim3(16, 16), 256, 0, stream>>>(wv, wvT, 1024);
  cast_transpose_k<<<dim3(4, 16), 256, 0, stream>>>(egw1, w1T, 256);
  fm_cast_t<<<64, 256, 0, stream>>>(fm, fmbT);
  proj_bf16<<<dim3(8, 16, 3), 256, 0, stream>>>(hsb, wqT, wkT, wvT, sq, sk, vv);
  cast_bf16_k<<<2048, 256, 0, stream>>>(sq, sqb);
  coarse_kernel<<<dim3(16, 32), 256, 0, stream>>>(sq, mc, zc, fn, co, rels, parts);
  cast_bf16_k<<<2048, 256, 0, stream>>>(co, cob);
  mm_bf16<<<dim3(2, 16), 256, 0, stream>>>(cob, w1T, h1, 256, 0);          // eg stage 1
  eg_fin<<<512, 256, 0, stream>>>(h1, egb1, egw2, egb2, ep);               // eg stage 2
  weights_kernel<<<1, 64, 0, stream>>>(parts, wts);
  fine_mfma<<<dim3(16, 16), 256, 0, stream>>>(sqb, fmbT, rels, wts, ep, co, mo);
  chunk_state_kernel<<<dim3(16, 32), 256, 0, stream>>>(sk, vv, states);
  scan_kernel<<<260, 256, 0, stream>>>(states);
  local_attn_kernel<<<dim3(16, 32), 256, 0, stream>>>(sq, sk, vv, states, lo);
  combine_kernel<<<8192, 256, 0, stream>>>(mo, lo, mg, cb);
  cast_bf16_k<<<2048, 256, 0, stream>>>(cb, cbb);
  cast_transpose_k<<<dim3(16, 16), 256, 0, stream>>>(wo, woT, 1024);
  mm_bf16<<<dim3(8, 16), 256, 0, stream>>>(cbb, woT, out, 1024, 0);
}

// Round 10
// 165.944 us; speedup vs baseline: 2.7115x; 1.2005x over previous
//
#include <hip/hip_runtime.h>
#include <cmath>

#define EPSF 1e-6f
#define LDK 72

// ---------------------------------------------------------------------------
// Shapes: B=1, S=2048, H=16, D=64, hid=1024
// R6: QKV+out-proj MFMA. R7: eg MFMA. R8: fine MFMA + scan re-grid.
// R9: coarse + local_attn -> MFMA; dens via extra MFMA columns; disjoint ws.
// ---------------------------------------------------------------------------

typedef __attribute__((ext_vector_type(8))) short bf16x8;
typedef __attribute__((ext_vector_type(4))) float f32x4;
typedef __attribute__((ext_vector_type(8))) unsigned short u16x8;

__device__ __forceinline__ float wave_allsum(float v) {
#pragma unroll
  for (int off = 32; off > 0; off >>= 1) v += __shfl_xor(v, off, 64);
  return v;
}

__device__ __forceinline__ unsigned short f2bf(float f) {  // RNE f32->bf16
  unsigned int u = __float_as_uint(f);
  unsigned int r = (u + 0x7fffu + ((u >> 16) & 1u)) >> 16;
  return (unsigned short)r;
}

// ---------------- K0: coarse memory = sum of fine banks --------------------
__global__ __launch_bounds__(256) void k0_summem(const float* __restrict__ FM,
    const float* __restrict__ FN, float* __restrict__ MC, float* __restrict__ ZC)
{
  int idx = blockIdx.x * 256 + threadIdx.x;
  if (idx < 65536)
    MC[idx] = FM[idx] + FM[65536 + idx] + FM[131072 + idx] + FM[196608 + idx];
  if (idx < 1024)
    ZC[idx] = FN[idx] + FN[1024 + idx] + FN[2048 + idx] + FN[3072 + idx];
}

// ---------------- cast kernels ---------------------------------------------
__global__ __launch_bounds__(256) void cast_bf16_k(const float* __restrict__ X,
    unsigned short* __restrict__ Y)
{
  int i = blockIdx.x * 256 + threadIdx.x;
  float4 v = *reinterpret_cast<const float4*>(X + i * 4);
  ushort4 o; o.x = f2bf(v.x); o.y = f2bf(v.y); o.z = f2bf(v.z); o.w = f2bf(v.w);
  *reinterpret_cast<ushort4*>(Y + i * 4) = o;
}

// sq/sk/vv -> bf16, z selects
__global__ __launch_bounds__(256) void cast_qkv(const float* __restrict__ SQ,
    const float* __restrict__ SK, const float* __restrict__ VV,
    unsigned short* __restrict__ SQB, unsigned short* __restrict__ SKB,
    unsigned short* __restrict__ VVB)
{
  int z = blockIdx.y;
  const float* X = (z == 0) ? SQ : (z == 1) ? SK : VV;
  unsigned short* Y = (z == 0) ? SQB : (z == 1) ? SKB : VVB;
  int i = blockIdx.x * 256 + threadIdx.x;
  float4 v = *reinterpret_cast<const float4*>(X + i * 4);
  ushort4 o; o.x = f2bf(v.x); o.y = f2bf(v.y); o.z = f2bf(v.z); o.w = f2bf(v.w);
  *reinterpret_cast<ushort4*>(Y + i * 4) = o;
}

// W [1024][N] f32 -> WT [N][1024] bf16 (generic, for egw1)
__global__ __launch_bounds__(256) void cast_transpose_k(const float* __restrict__ W,
    unsigned short* __restrict__ WT, int N)
{
  __shared__ float tile[64][65];
  int n0 = blockIdx.x * 64, k0 = blockIdx.y * 64;
  int tid = threadIdx.x;
  for (int i = tid; i < 4096; i += 256) {
    int r = i >> 6, c = i & 63;
    tile[r][c] = W[(k0 + r) * N + n0 + c];
  }
  __syncthreads();
  for (int i = tid; i < 1024; i += 256) {
    int r = i >> 4, c4 = (i & 15) * 4;
    ushort4 o;
    o.x = f2bf(tile[c4 + 0][r]); o.y = f2bf(tile[c4 + 1][r]);
    o.z = f2bf(tile[c4 + 2][r]); o.w = f2bf(tile[c4 + 3][r]);
    *reinterpret_cast<ushort4*>(&WT[(n0 + r) * 1024 + k0 + c4]) = o;
  }
}

// wq/wk/wv/wo fused cast+transpose (z selects)
__global__ __launch_bounds__(256) void cast_w4(const float* __restrict__ W0,
    const float* __restrict__ W1, const float* __restrict__ W2, const float* __restrict__ W3,
    unsigned short* __restrict__ T0, unsigned short* __restrict__ T1,
    unsigned short* __restrict__ T2, unsigned short* __restrict__ T3)
{
  int z = blockIdx.z;
  const float* W = (z == 0) ? W0 : (z == 1) ? W1 : (z == 2) ? W2 : W3;
  unsigned short* WT = (z == 0) ? T0 : (z == 1) ? T1 : (z == 2) ? T2 : T3;
  __shared__ float tile[64][65];
  int n0 = blockIdx.x * 64, k0 = blockIdx.y * 64;
  int tid = threadIdx.x;
  for (int i = tid; i < 4096; i += 256) {
    int r = i >> 6, c = i & 63;
    tile[r][c] = W[(k0 + r) * 1024 + n0 + c];
  }
  __syncthreads();
  for (int i = tid; i < 1024; i += 256) {
    int r = i >> 4, c4 = (i & 15) * 4;
    ushort4 o;
    o.x = f2bf(tile[c4 + 0][r]); o.y = f2bf(tile[c4 + 1][r]);
    o.z = f2bf(tile[c4 + 2][r]); o.w = f2bf(tile[c4 + 3][r]);
    *reinterpret_cast<ushort4*>(&WT[(n0 + r) * 1024 + k0 + c4]) = o;
  }
}

// X f32 [nmats][64][64] -> XT bf16 [nmats][e][dp] (per-matrix transpose)
__global__ __launch_bounds__(256) void fm_cast_t(const float* __restrict__ FM,
    unsigned short* __restrict__ FMT)
{
  __shared__ float tile[64][65];
  int b = blockIdx.x, tid = threadIdx.x;
  const float* src = FM + b * 4096;
  for (int i = tid; i < 4096; i += 256) tile[i >> 6][i & 63] = src[i];
  __syncthreads();
  unsigned short* dst = FMT + b * 4096;
  for (int i = tid; i < 4096; i += 256) {
    int e = i >> 6, dp = i & 63;
    dst[e * 64 + dp] = f2bf(tile[dp][e]);
  }
}

// ---------------- bf16 MFMA GEMM: C[M][ldc] = A[M][1024] x BT[N][1024]^T ----
__global__ __launch_bounds__(256) void mm_bf16(const unsigned short* __restrict__ A,
    const unsigned short* __restrict__ BT, float* __restrict__ C, int ldc, int act)
{
  __shared__ unsigned short As[128 * LDK];
  __shared__ unsigned short Bs[128 * LDK];
  int tid = threadIdx.x;
  int m0 = blockIdx.y * 128, n0 = blockIdx.x * 128;
  int wid = tid >> 6, lane = tid & 63;
  int wr = wid >> 1, wc = wid & 1;
  int lr = lane & 15, lg = lane >> 4;

  f32x4 acc[4][4];
#pragma unroll
  for (int m = 0; m < 4; ++m)
#pragma unroll
    for (int n = 0; n < 4; ++n)
#pragma unroll
      for (int r = 0; r < 4; ++r) acc[m][n][r] = 0.f;

  for (int kt = 0; kt < 16; ++kt) {
    int k0 = kt * 64;
#pragma unroll
    for (int p = 0; p < 4; ++p) {
      int c = p * 256 + tid;
      int row = c >> 3, k8 = c & 7;
      u16x8 va = *reinterpret_cast<const u16x8*>(A + (m0 + row) * 1024 + k0 + k8 * 8);
      *reinterpret_cast<u16x8*>(&As[row * LDK + k8 * 8]) = va;
      u16x8 vb = *reinterpret_cast<const u16x8*>(BT + (n0 + row) * 1024 + k0 + k8 * 8);
      *reinterpret_cast<u16x8*>(&Bs[row * LDK + k8 * 8]) = vb;
    }
    __syncthreads();
#pragma unroll
    for (int kk = 0; kk < 2; ++kk) {
      bf16x8 af[4], bfr[4];
#pragma unroll
      for (int m = 0; m < 4; ++m)
        af[m] = *reinterpret_cast<const bf16x8*>(&As[(wr * 64 + m * 16 + lr) * LDK + kk * 32 + lg * 8]);
#pragma unroll
      for (int n = 0; n < 4; ++n)
        bfr[n] = *reinterpret_cast<const bf16x8*>(&Bs[(wc * 64 + n * 16 + lr) * LDK + kk * 32 + lg * 8]);
#pragma unroll
      for (int m = 0; m < 4; ++m)
#pragma unroll
        for (int n = 0; n < 4; ++n)
          acc[m][n] = __builtin_amdgcn_mfma_f32_16x16x32_bf16(af[m], bfr[n], acc[m][n], 0, 0, 0);
    }
    __syncthreads();
  }
#pragma unroll
  for (int m = 0; m < 4; ++m)
#pragma unroll
    for (int n = 0; n < 4; ++n)
#pragma unroll
      for (int r = 0; r < 4; ++r) {
        float v = acc[m][n][r];
        if (act) v = v > 0.f ? v + 1.f : expf(v);
        C[(m0 + wr * 64 + m * 16 + lg * 4 + r) * ldc + n0 + wc * 64 + n * 16 + lr] = v;
      }
}

// fused QKV projections (z = q/k/v)
__global__ __launch_bounds__(256) void proj_bf16(const unsigned short* __restrict__ A,
    const unsigned short* __restrict__ WqT, const unsigned short* __restrict__ WkT,
    const unsigned short* __restrict__ WvT,
    float* __restrict__ Oq, float* __restrict__ Ok, float* __restrict__ Ov)
{
  int z = blockIdx.z;
  const unsigned short* BT = (z == 0) ? WqT : (z == 1) ? WkT : WvT;
  float* C = (z == 0) ? Oq : (z == 1) ? Ok : Ov;

  __shared__ unsigned short As[128 * LDK];
  __shared__ unsigned short Bs[128 * LDK];
  int tid = threadIdx.x;
  int m0 = blockIdx.y * 128, n0 = blockIdx.x * 128;
  int wid = tid >> 6, lane = tid & 63;
  int wr = wid >> 1, wc = wid & 1;
  int lr = lane & 15, lg = lane >> 4;
  int act = (z < 2) ? 1 : 0;

  f32x4 acc[4][4];
#pragma unroll
  for (int m = 0; m < 4; ++m)
#pragma unroll
    for (int n = 0; n < 4; ++n)
#pragma unroll
      for (int r = 0; r < 4; ++r) acc[m][n][r] = 0.f;

  for (int kt = 0; kt < 16; ++kt) {
    int k0 = kt * 64;
#pragma unroll
    for (int p = 0; p < 4; ++p) {
      int c = p * 256 + tid;
      int row = c >> 3, k8 = c & 7;
      u16x8 va = *reinterpret_cast<const u16x8*>(A + (m0 + row) * 1024 + k0 + k8 * 8);
      *reinterpret_cast<u16x8*>(&As[row * LDK + k8 * 8]) = va;
      u16x8 vb = *reinterpret_cast<const u16x8*>(BT + (n0 + row) * 1024 + k0 + k8 * 8);
      *reinterpret_cast<u16x8*>(&Bs[row * LDK + k8 * 8]) = vb;
    }
    __syncthreads();
#pragma unroll
    for (int kk = 0; kk < 2; ++kk) {
      bf16x8 af[4], bfr[4];
#pragma unroll
      for (int m = 0; m < 4; ++m)
        af[m] = *reinterpret_cast<const bf16x8*>(&As[(wr * 64 + m * 16 + lr) * LDK + kk * 32 + lg * 8]);
#pragma unroll
      for (int n = 0; n < 4; ++n)
        bfr[n] = *reinterpret_cast<const bf16x8*>(&Bs[(wc * 64 + n * 16 + lr) * LDK + kk * 32 + lg * 8]);
#pragma unroll
      for (int m = 0; m < 4; ++m)
#pragma unroll
        for (int n = 0; n < 4; ++n)
          acc[m][n] = __builtin_amdgcn_mfma_f32_16x16x32_bf16(af[m], bfr[n], acc[m][n], 0, 0, 0);
    }
    __syncthreads();
  }
#pragma unroll
  for (int m = 0; m < 4; ++m)
#pragma unroll
    for (int n = 0; n < 4; ++n)
#pragma unroll
      for (int r = 0; r < 4; ++r) {
        float v = acc[m][n][r];
        if (act) v = v > 0.f ? v + 1.f : expf(v);
        C[(m0 + wr * 64 + m * 16 + lg * 4 + r) * 1024 + n0 + wc * 64 + n * 16 + lr] = v;
      }
}

// ---------------- eg stage 2 ------------------------------------------------
__global__ __launch_bounds__(256) void eg_fin(const float* __restrict__ H1,
    const float* __restrict__ B1, const float* __restrict__ W2,
    const float* __restrict__ B2, float* __restrict__ EP)
{
  int wid = threadIdx.x >> 6, lane = threadIdx.x & 63;
  int s = blockIdx.x * 4 + wid;
  float4 h = *reinterpret_cast<const float4*>(H1 + s * 256 + lane * 4);
  float4 b = *reinterpret_cast<const float4*>(B1 + lane * 4);
  float4 w = *reinterpret_cast<const float4*>(W2 + lane * 4);
  float v = fmaxf(h.x + b.x, 0.f) * w.x + fmaxf(h.y + b.y, 0.f) * w.y
          + fmaxf(h.z + b.z, 0.f) * w.z + fmaxf(h.w + b.w, 0.f) * w.w;
  v = wave_allsum(v);
  if (lane == 0) EP[s] = 1.f / (1.f + expf(-(v + B2[0])));
}

// ---------------- rels: relevance dots (fp32) -------------------------------
// relb[0]=z_coarse, relb[1..4]=fine banks. Writes RELC, RELS, PARTS.
__global__ __launch_bounds__(256) void rels_kernel(const float* __restrict__ SQ,
    const float* __restrict__ ZC, const float* __restrict__ FN,
    float* __restrict__ RELC, float* __restrict__ RELS, float* __restrict__ PARTS)
{
  int h = blockIdx.x, st = blockIdx.y, tid = threadIdx.x;
  int s0 = st * 64;
  __shared__ float sqT[64][68];
  __shared__ float zf[5][64];
  __shared__ float relb[5][64];
  for (int idx = tid; idx < 4096; idx += 256) {
    int r = idx >> 6, d = idx & 63;
    sqT[d][r] = SQ[(s0 + r) * 1024 + h * 64 + d];
  }
  for (int idx = tid; idx < 320; idx += 256) {
    int w = idx >> 6, d = idx & 63;
    zf[w][d] = (w == 0) ? ZC[h * 64 + d] : FN[(w - 1) * 1024 + h * 64 + d];
  }
  __syncthreads();
  {
    int s = tid & 63, wh = tid >> 6;
    float r = 0.f;
    for (int dp = 0; dp < 64; ++dp) r += sqT[dp][s] * zf[wh][dp];
    relb[wh][s] = r;
    if (wh == 0) {
      float r4 = 0.f;
      for (int dp = 0; dp < 64; ++dp) r4 += sqT[dp][s] * zf[4][dp];
      relb[4][s] = r4;
    }
  }
  __syncthreads();
  if (tid < 64) {
    RELC[h * 2048 + s0 + tid] = relb[0][tid];
#pragma unroll
    for (int f = 0; f < 4; ++f)
      RELS[f * 32768 + h * 2048 + s0 + tid] = relb[1 + f][tid];
#pragma unroll
    for (int f = 0; f < 4; ++f) {
      float v = wave_allsum(relb[1 + f][tid]);
      if (tid == 0) PARTS[f * 512 + h * 32 + st] = v;
    }
  }
}

// ---------------- coarse retrieval, bf16 MFMA -------------------------------
__global__ __launch_bounds__(256) void coarse_mfma(const unsigned short* __restrict__ SQB,
    const unsigned short* __restrict__ MCT, const float* __restrict__ RELC,
    float* __restrict__ CO)
{
  int h = blockIdx.x, st = blockIdx.y, tid = threadIdx.x;
  int w = tid >> 6, lane = tid & 63, lr = lane & 15, lg = lane >> 4;
  int s0 = st * 128;
  __shared__ unsigned short A_lds[128 * LDK];
  __shared__ unsigned short B_lds[64 * LDK];
#pragma unroll
  for (int p = 0; p < 4; ++p) {
    int c = p * 256 + tid;
    int row = c >> 3, k8 = c & 7;
    *reinterpret_cast<u16x8*>(&A_lds[row * LDK + k8 * 8]) =
        *reinterpret_cast<const u16x8*>(SQB + (s0 + row) * 1024 + h * 64 + k8 * 8);
  }
#pragma unroll
  for (int p = 0; p < 2; ++p) {
    int c = p * 256 + tid;
    int e = c >> 3, k8 = c & 7;
    *reinterpret_cast<u16x8*>(&B_lds[e * LDK + k8 * 8]) =
        *reinterpret_cast<const u16x8*>(MCT + h * 4096 + e * 64 + k8 * 8);
  }
  __syncthreads();

  f32x4 acc[2][4];
#pragma unroll
  for (int m = 0; m < 2; ++m)
#pragma unroll
    for (int n = 0; n < 4; ++n)
#pragma unroll
      for (int r = 0; r < 4; ++r) acc[m][n][r] = 0.f;

#pragma unroll
  for (int kk = 0; kk < 2; ++kk) {
    bf16x8 af[2], bfr[4];
#pragma unroll
    for (int m = 0; m < 2; ++m)
      af[m] = *reinterpret_cast<const bf16x8*>(&A_lds[(w * 32 + m * 16 + lr) * LDK + kk * 32 + lg * 8]);
#pragma unroll
    for (int n = 0; n < 4; ++n)
      bfr[n] = *reinterpret_cast<const bf16x8*>(&B_lds[(n * 16 + lr) * LDK + kk * 32 + lg * 8]);
#pragma unroll
    for (int m = 0; m < 2; ++m)
#pragma unroll
      for (int n = 0; n < 4; ++n)
        acc[m][n] = __builtin_amdgcn_mfma_f32_16x16x32_bf16(af[m], bfr[n], acc[m][n], 0, 0, 0);
  }
#pragma unroll
  for (int m = 0; m < 2; ++m)
#pragma unroll
    for (int r = 0; r < 4; ++r) {
      int s = s0 + w * 32 + m * 16 + lg * 4 + r;
      float rc = fmaxf(RELC[h * 2048 + s], EPSF);
#pragma unroll
      for (int n = 0; n < 4; ++n)
        CO[s * 1024 + h * 64 + n * 16 + lr] = acc[m][n][r] / rc;
    }
}

// ---------------- K4: bank softmax weights ----------------------------------
__global__ void weights_kernel(const float* __restrict__ P, float* __restrict__ W)
{
  int h = threadIdx.x;
  if (h >= 16) return;
  float r[4];
#pragma unroll
  for (int f = 0; f < 4; ++f) {
    float s = 0.f;
    for (int t = 0; t < 32; ++t) s += P[f * 512 + h * 32 + t];
    r[f] = s * (1.f / 2048.f);
  }
  float m = fmaxf(fmaxf(r[0], r[1]), fmaxf(r[2], r[3]));
  float e0 = expf(r[0] - m), e1 = expf(r[1] - m), e2 = expf(r[2] - m), e3 = expf(r[3] - m);
  float inv = 1.f / (e0 + e1 + e2 + e3);
  W[0 * 16 + h] = e0 * inv; W[1 * 16 + h] = e1 * inv;
  W[2 * 16 + h] = e2 * inv; W[3 * 16 + h] = e3 * inv;
}

// ---------------- fine retrieval + combine, bf16 MFMA -----------------------
__global__ __launch_bounds__(256) void fine_mfma(const unsigned short* __restrict__ SQB,
    const unsigned short* __restrict__ FMT, const float* __restrict__ RELS,
    const float* __restrict__ WT, const float* __restrict__ EP,
    const float* __restrict__ CO, float* __restrict__ MO)
{
  int h = blockIdx.x, st = blockIdx.y;
  int tid = threadIdx.x;
  int w = tid >> 6, lane = tid & 63;
  int lr = lane & 15, lg = lane >> 4;
  int s0 = st * 128;

  __shared__ unsigned short A_lds[128 * LDK];
  __shared__ unsigned short B_lds[4 * 64 * LDK];
  __shared__ float w4s[4];
  if (tid < 4) w4s[tid] = WT[tid * 16 + h];

#pragma unroll
  for (int p = 0; p < 4; ++p) {
    int c = p * 256 + tid;
    int row = c >> 3, k8 = c & 7;
    *reinterpret_cast<u16x8*>(&A_lds[row * LDK + k8 * 8]) =
        *reinterpret_cast<const u16x8*>(SQB + (s0 + row) * 1024 + h * 64 + k8 * 8);
  }
#pragma unroll
  for (int p = 0; p < 8; ++p) {
    int c = p * 256 + tid;
    int f = c >> 9, rem = c & 511;
    int e = rem >> 3, k8 = rem & 7;
    *reinterpret_cast<u16x8*>(&B_lds[(f * 64 + e) * LDK + k8 * 8]) =
        *reinterpret_cast<const u16x8*>(FMT + (f * 16 + h) * 4096 + e * 64 + k8 * 8);
  }
  __syncthreads();

  f32x4 acc[4][2][4];
#pragma unroll
  for (int f = 0; f < 4; ++f)
#pragma unroll
    for (int m = 0; m < 2; ++m)
#pragma unroll
      for (int n = 0; n < 4; ++n)
#pragma unroll
        for (int r = 0; r < 4; ++r) acc[f][m][n][r] = 0.f;

#pragma unroll
  for (int kk = 0; kk < 2; ++kk) {
    bf16x8 af[2];
#pragma unroll
    for (int m = 0; m < 2; ++m)
      af[m] = *reinterpret_cast<const bf16x8*>(&A_lds[(w * 32 + m * 16 + lr) * LDK + kk * 32 + lg * 8]);
#pragma unroll
    for (int f = 0; f < 4; ++f) {
      bf16x8 bf4[4];
#pragma unroll
      for (int n = 0; n < 4; ++n)
        bf4[n] = *reinterpret_cast<const bf16x8*>(&B_lds[(f * 64 + n * 16 + lr) * LDK + kk * 32 + lg * 8]);
#pragma unroll
      for (int m = 0; m < 2; ++m)
#pragma unroll
        for (int n = 0; n < 4; ++n)
          acc[f][m][n] = __builtin_amdgcn_mfma_f32_16x16x32_bf16(af[m], bf4[n], acc[f][m][n], 0, 0, 0);
    }
  }

#pragma unroll
  for (int m = 0; m < 2; ++m)
#pragma unroll
    for (int r = 0; r < 4; ++r) {
      int s = s0 + w * 32 + m * 16 + lg * 4 + r;
      float e = EP[s];
      float i0 = w4s[0] / fmaxf(RELS[0 * 32768 + h * 2048 + s], EPSF);
      float i1 = w4s[1] / fmaxf(RELS[1 * 32768 + h * 2048 + s], EPSF);
      float i2 = w4s[2] / fmaxf(RELS[2 * 32768 + h * 2048 + s], EPSF);
      float i3 = w4s[3] / fmaxf(RELS[3 * 32768 + h * 2048 + s], EPSF);
#pragma unroll
      for (int n = 0; n < 4; ++n) {
        int dg = h * 64 + n * 16 + lr;
        float fine = acc[0][m][n][r] * i0 + acc[1][m][n][r] * i1
                   + acc[2][m][n][r] * i2 + acc[3][m][n][r] * i3;
        float cv = CO[s * 1024 + dg];
        MO[s * 1024 + dg] = e * fine + (1.f - e) * cv;
      }
    }
}

// ---------------- K6: per-chunk KV state sums (fp32) ------------------------
__global__ __launch_bounds__(256) void chunk_state_kernel(const float* __restrict__ SK,
    const float* __restrict__ V, float* __restrict__ ST)
{
  int h = blockIdx.x, c = blockIdx.y, tid = threadIdx.x;
  __shared__ __align__(16) float sk[64][68];
  __shared__ __align__(16) float vv[64][68];
  for (int idx = tid; idx < 4096; idx += 256) {
    int s = idx >> 6, d = idx & 63;
    sk[s][d] = SK[(c * 64 + s) * 1024 + h * 64 + d];
    vv[s][d] = V [(c * 64 + s) * 1024 + h * 64 + d];
  }
  __syncthreads();
  int tx = tid & 15, dy = tid >> 4;
  float acc[4][4] = {{0.f}};
  for (int s = 0; s < 64; ++s) {
    float4 kd = *reinterpret_cast<const float4*>(&sk[s][dy * 4]);
    float4 ve = *reinterpret_cast<const float4*>(&vv[s][tx * 4]);
    float ka[4] = {kd.x, kd.y, kd.z, kd.w};
    float vb[4] = {ve.x, ve.y, ve.z, ve.w};
#pragma unroll
    for (int i = 0; i < 4; ++i)
#pragma unroll
      for (int j = 0; j < 4; ++j) acc[i][j] += ka[i] * vb[j];
  }
  float* base = ST + (h * 32 + c) * 4160;
#pragma unroll
  for (int i = 0; i < 4; ++i) {
    float4 o; o.x = acc[i][0]; o.y = acc[i][1]; o.z = acc[i][2]; o.w = acc[i][3];
    *reinterpret_cast<float4*>(&base[(dy * 4 + i) * 64 + tx * 4]) = o;
  }
  if (tid < 64) {
    float ks = 0.f;
    for (int s = 0; s < 64; ++s) ks += sk[s][tid];
    base[4096 + tid] = ks;
  }
}

// ---------------- K7: exclusive prefix over chunks --------------------------
__global__ __launch_bounds__(256) void scan_kernel(float* __restrict__ ST)
{
  int gidx = blockIdx.x * 256 + threadIdx.x;
  int h = gidx / 4160, idx = gidx - h * 4160;
  if (h >= 16) return;
  float run = 0.f;
#pragma unroll 4
  for (int c = 0; c < 32; ++c) {
    float* p = ST + (h * 32 + c) * 4160 + idx;
    float t = *p; *p = run; run += t;
  }
}

// ---------------- K8': causal linear attention, bf16 MFMA -------------------
// N padded to 80: col 64 of KVprevT = kprev (inter den), col 64 of vT = ones
// (intra den). dens clipped fp32 in epilogue; mask applied to fp32 scores.
__global__ __launch_bounds__(256) void lattn_mfma(const unsigned short* __restrict__ SQB,
    const unsigned short* __restrict__ SKB, const unsigned short* __restrict__ VVB,
    const float* __restrict__ ST, float* __restrict__ OUT)
{
  int h = blockIdx.x, c = blockIdx.y, tid = threadIdx.x;
  int w = tid >> 6, lane = tid & 63, lr = lane & 15, lg = lane >> 4;
  int sb = c * 64;
  const float* st = ST + (h * 32 + c) * 4160;

  __shared__ unsigned short A_lds[64 * LDK];   // sigma_q rows
  __shared__ unsigned short K_lds[64 * LDK];   // sigma_k rows
  __shared__ unsigned short P_lds[80 * LDK];   // KVprev^T rows; row64=kprev
  __shared__ unsigned short V_lds[80 * LDK];   // v^T rows; row64=ones
  __shared__ unsigned short S_lds[64 * LDK];   // masked scores

#pragma unroll
  for (int p = 0; p < 2; ++p) {
    int cc = p * 256 + tid;
    int row = cc >> 3, k8 = cc & 7;
    *reinterpret_cast<u16x8*>(&A_lds[row * LDK + k8 * 8]) =
        *reinterpret_cast<const u16x8*>(SQB + (sb + row) * 1024 + h * 64 + k8 * 8);
    *reinterpret_cast<u16x8*>(&K_lds[row * LDK + k8 * 8]) =
        *reinterpret_cast<const u16x8*>(SKB + (sb + row) * 1024 + h * 64 + k8 * 8);
  }
  for (int i = tid; i < 4096; i += 256) {          // KVprev [d][e] -> P[e][d]
    int d = i >> 6, e = i & 63;
    P_lds[e * LDK + d] = f2bf(st[i]);
  }
#pragma unroll
  for (int p = 0; p < 2; ++p) {                    // v [t][e] -> V[e][t]
    int cc = p * 256 + tid;
    int t = cc >> 3, e8 = cc & 7;
    u16x8 v = *reinterpret_cast<const u16x8*>(VVB + (sb + t) * 1024 + h * 64 + e8 * 8);
#pragma unroll
    for (int j = 0; j < 8; ++j) V_lds[(e8 * 8 + j) * LDK + t] = (unsigned short)v[j];
  }
  if (tid < 64) {
    P_lds[64 * LDK + tid] = f2bf(st[4096 + tid]);  // kprev
    V_lds[64 * LDK + tid] = 0x3F80;                // ones (bf16 1.0)
  }
  for (int i = tid; i < 15 * 64; i += 256) {       // zero pad rows 65..79
    int row = 65 + (i >> 6), col = i & 63;
    P_lds[row * LDK + col] = 0;
    V_lds[row * LDK + col] = 0;
  }
  __syncthreads();

  // phase A: inter-chunk num + den (k = d)
  f32x4 acc_i[5];
#pragma unroll
  for (int n = 0; n < 5; ++n)
#pragma unroll
    for (int r = 0; r < 4; ++r) acc_i[n][r] = 0.f;
#pragma unroll
  for (int kk = 0; kk < 2; ++kk) {
    bf16x8 af = *reinterpret_cast<const bf16x8*>(&A_lds[(w * 16 + lr) * LDK + kk * 32 + lg * 8]);
#pragma unroll
    for (int n = 0; n < 5; ++n) {
      bf16x8 bfr = *reinterpret_cast<const bf16x8*>(&P_lds[(n * 16 + lr) * LDK + kk * 32 + lg * 8]);
      acc_i[n] = __builtin_amdgcn_mfma_f32_16x16x32_bf16(af, bfr, acc_i[n], 0, 0, 0);
    }
  }
  // phase B: scores (k = d)
  f32x4 acc_s[4];
#pragma unroll
  for (int n = 0; n < 4; ++n)
#pragma unroll
    for (int r = 0; r < 4; ++r) acc_s[n][r] = 0.f;
#pragma unroll
  for (int kk = 0; kk < 2; ++kk) {
    bf16x8 af = *reinterpret_cast<const bf16x8*>(&A_lds[(w * 16 + lr) * LDK + kk * 32 + lg * 8]);
#pragma unroll
    for (int n = 0; n < 4; ++n) {
      bf16x8 bfr = *reinterpret_cast<const bf16x8*>(&K_lds[(n * 16 + lr) * LDK + kk * 32 + lg * 8]);
      acc_s[n] = __builtin_amdgcn_mfma_f32_16x16x32_bf16(af, bfr, acc_s[n], 0, 0, 0);
    }
  }
  // mask + write S (causal within chunk: t <= s)
#pragma unroll
  for (int n = 0; n < 4; ++n)
#pragma unroll
    for (int r = 0; r < 4; ++r) {
      int s_loc = w * 16 + lg * 4 + r, t = n * 16 + lr;
      float v = (t <= s_loc) ? acc_s[n][r] : 0.f;
      S_lds[s_loc * LDK + t] = f2bf(v);
    }
  __syncthreads();
  // phase C: PV + intra den (k = t)
  f32x4 acc_p[5];
#pragma unroll
  for (int n = 0; n < 5; ++n)
#pragma unroll
    for (int r = 0; r < 4; ++r) acc_p[n][r] = 0.f;
#pragma unroll
  for (int kk = 0; kk < 2; ++kk) {
    bf16x8 af = *reinterpret_cast<const bf16x8*>(&S_lds[(w * 16 + lr) * LDK + kk * 32 + lg * 8]);
#pragma unroll
    for (int n = 0; n < 5; ++n) {
      bf16x8 bfr = *reinterpret_cast<const bf16x8*>(&V_lds[(n * 16 + lr) * LDK + kk * 32 + lg * 8]);
      acc_p[n] = __builtin_amdgcn_mfma_f32_16x16x32_bf16(af, bfr, acc_p[n], 0, 0, 0);
    }
  }
  // epilogue
#pragma unroll
  for (int r = 0; r < 4; ++r) {
    float den = acc_i[4][r] + acc_p[4][r];         // valid at lr==0
    den = __shfl(den, lane & 48);                  // broadcast from lr==0 of this lg
    den = fmaxf(den, EPSF);
    int s = sb + w * 16 + lg * 4 + r;
#pragma unroll
    for (int n = 0; n < 4; ++n)
      OUT[s * 1024 + h * 64 + n * 16 + lr] = (acc_i[n][r] + acc_p[n][r]) / den;
  }
}

// ---------------- K9: gate combine -> bf16 ----------------------------------
__global__ __launch_bounds__(256) void combine_bf16(const float* __restrict__ MO,
    const float* __restrict__ LO, const float* __restrict__ MG,
    unsigned short* __restrict__ CBB)
{
  int i = blockIdx.x * 256 + threadIdx.x;          // x4 elements
  float4 m4 = *reinterpret_cast<const float4*>(MO + i * 4);
  float4 l4 = *reinterpret_cast<const float4*>(LO + i * 4);
  int hh = ((i * 4) >> 6) & 15;
  float g = 1.f / (1.f + expf(-MG[hh]));
  ushort4 o;
  o.x = f2bf(g * m4.x + (1.f - g) * l4.x);
  o.y = f2bf(g * m4.y + (1.f - g) * l4.y);
  o.z = f2bf(g * m4.z + (1.f - g) * l4.z);
  o.w = f2bf(g * m4.w + (1.f - g) * l4.w);
  *reinterpret_cast<ushort4*>(CBB + i * 4) = o;
}

// ---------------------------------------------------------------------------
extern "C" void kernel_launch(void* const* d_in, const int* in_sizes, int n_in,
                              void* d_out, int out_size, void* d_ws, size_t ws_size,
                              hipStream_t stream)
{
  const float* hs   = (const float*)d_in[0];
  const float* wq   = (const float*)d_in[1];
  const float* wk   = (const float*)d_in[2];
  const float* wv   = (const float*)d_in[3];
  const float* wo   = (const float*)d_in[4];
  const float* mg   = (const float*)d_in[5];
  const float* egw1 = (const float*)d_in[6];
  const float* egb1 = (const float*)d_in[7];
  const float* egw2 = (const float*)d_in[8];
  const float* egb2 = (const float*)d_in[9];
  const float* fm   = (const float*)d_in[10];
  const float* fn   = (const float*)d_in[11];
  float* out = (float*)d_out;

  // ---- disjoint workspace layout (ws is 268 MB; total use ~97 MB) ----
  float* ws     = (float*)d_ws;
  float* sq     = ws;                       // [2048][1024]
  float* sk     = sq + 2097152;
  float* vv     = sk + 2097152;
  float* co     = vv + 2097152;
  float* mo     = co + 2097152;
  float* lo     = mo + 2097152;
  float* mc     = lo + 2097152;             // 65536
  float* zc     = mc + 65536;               // 1024
  float* rels   = zc + 1024;                // 131072
  float* parts  = rels + 131072;            // 2048
  float* wts    = parts + 2048;             // 64
  float* ep     = wts + 64;                 // 2048
  float* relc   = ep + 2048;                // 32768
  float* states = relc + 32768;             // 2129920
  float* h1     = states + 2129920;         // 524288
  unsigned short* hsb  = (unsigned short*)(h1 + 524288);   // 2097152 each
  unsigned short* sqb  = hsb + 2097152;
  unsigned short* skb  = sqb + 2097152;
  unsigned short* vvb  = skb + 2097152;
  unsigned short* cob  = vvb + 2097152;
  unsigned short* cbb  = cob + 2097152;
  unsigned short* wqT  = cbb + 2097152;     // 1048576 each
  unsigned short* wkT  = wqT + 1048576;
  unsigned short* wvT  = wkT + 1048576;
  unsigned short* woT  = wvT + 1048576;
  unsigned short* w1T  = woT + 1048576;     // 262144
  unsigned short* fmbT = w1T + 262144;      // 262144
  unsigned short* mcT  = fmbT + 262144;     // 65536

  k0_summem<<<256, 256, 0, stream>>>(fm, fn, mc, zc);
  cast_w4<<<dim3(16, 16, 4), 256, 0, stream>>>(wq, wk, wv, wo, wqT, wkT, wvT, woT);
  cast_transpose_k<<<dim3(4, 16), 256, 0, stream>>>(egw1, w1T, 256);
  fm_cast_t<<<64, 256, 0, stream>>>(fm, fmbT);
  cast_bf16_k<<<2048, 256, 0, stream>>>(hs, hsb);
  proj_bf16<<<dim3(8, 16, 3), 256, 0, stream>>>(hsb, wqT, wkT, wvT, sq, sk, vv);
  cast_qkv<<<dim3(2048, 3), 256, 0, stream>>>(sq, sk, vv, sqb, skb, vvb);
  rels_kernel<<<dim3(16, 32), 256, 0, stream>>>(sq, zc, fn, relc, rels, parts);
  fm_cast_t<<<16, 256, 0, stream>>>(mc, mcT);
  coarse_mfma<<<dim3(16, 16), 256, 0, stream>>>(sqb, mcT, relc, co);
  cast_bf16_k<<<2048, 256, 0, stream>>>(co, cob);
  mm_bf16<<<dim3(2, 16), 256, 0, stream>>>(cob, w1T, h1, 256, 0);   // eg stage 1
  eg_fin<<<512, 256, 0, stream>>>(h1, egb1, egw2, egb2, ep);
  weights_kernel<<<1, 64, 0, stream>>>(parts, wts);
  fine_mfma<<<dim3(16, 16), 256, 0, stream>>>(sqb, fmbT, rels, wts, ep, co, mo);
  chunk_state_kernel<<<dim3(16, 32), 256, 0, stream>>>(sk, vv, states);
  scan_kernel<<<260, 256, 0, stream>>>(states);
  lattn_mfma<<<dim3(16, 32), 256, 0, stream>>>(sqb, skb, vvb, states, lo);
  combine_bf16<<<2048, 256, 0, stream>>>(mo, lo, mg, cbb);
  mm_bf16<<<dim3(8, 16), 256, 0, stream>>>(cbb, woT, out, 1024, 0);
}

// Round 11
// 144.263 us; speedup vs baseline: 3.1190x; 1.1503x over previous
//
#include <hip/hip_runtime.h>
#include <cmath>

#define EPSF 1e-6f
#define LDK 72

// ---------------------------------------------------------------------------
// Shapes: B=1, S=2048, H=16, D=64, hid=1024
// R6-R9: all matmuls -> bf16 MFMA. R11: bf16-only qkv (no f32 round-trip),
// chunk_state -> MFMA (ones-column ksum), scan emits bf16 states,
// fused casts; 21 -> 17 launches.
// ---------------------------------------------------------------------------

typedef __attribute__((ext_vector_type(8))) short bf16x8;
typedef __attribute__((ext_vector_type(4))) float f32x4;
typedef __attribute__((ext_vector_type(8))) unsigned short u16x8;

__device__ __forceinline__ float wave_allsum(float v) {
#pragma unroll
  for (int off = 32; off > 0; off >>= 1) v += __shfl_xor(v, off, 64);
  return v;
}

__device__ __forceinline__ unsigned short f2bf(float f) {  // RNE f32->bf16
  unsigned int u = __float_as_uint(f);
  unsigned int r = (u + 0x7fffu + ((u >> 16) & 1u)) >> 16;
  return (unsigned short)r;
}
__device__ __forceinline__ float bf2f(unsigned short u) {
  return __uint_as_float(((unsigned int)u) << 16);
}

// ---------------- K0': coarse memory sum -> transposed bf16 + zc ------------
__global__ __launch_bounds__(256) void k0_mcT(const float* __restrict__ FM,
    const float* __restrict__ FN, unsigned short* __restrict__ MCT,
    float* __restrict__ ZC)
{
  int h = blockIdx.x, tid = threadIdx.x;
  __shared__ float tile[64][65];
  for (int i = tid; i < 4096; i += 256) {
    int dp = i >> 6, e = i & 63;
    float s = FM[(0 * 16 + h) * 4096 + i] + FM[(1 * 16 + h) * 4096 + i]
            + FM[(2 * 16 + h) * 4096 + i] + FM[(3 * 16 + h) * 4096 + i];
    tile[dp][e] = s;
  }
  if (tid < 64)
    ZC[h * 64 + tid] = FN[h * 64 + tid] + FN[1024 + h * 64 + tid]
                     + FN[2048 + h * 64 + tid] + FN[3072 + h * 64 + tid];
  __syncthreads();
  for (int i = tid; i < 4096; i += 256) {
    int e = i >> 6, dp = i & 63;
    MCT[h * 4096 + e * 64 + dp] = f2bf(tile[dp][e]);
  }
}

// ---------------- cast kernels ---------------------------------------------
__global__ __launch_bounds__(256) void cast_bf16_k(const float* __restrict__ X,
    unsigned short* __restrict__ Y)
{
  int i = blockIdx.x * 256 + threadIdx.x;
  float4 v = *reinterpret_cast<const float4*>(X + i * 4);
  ushort4 o; o.x = f2bf(v.x); o.y = f2bf(v.y); o.z = f2bf(v.z); o.w = f2bf(v.w);
  *reinterpret_cast<ushort4*>(Y + i * 4) = o;
}

// W [1024][N] f32 -> WT [N][1024] bf16 (generic, for egw1)
__global__ __launch_bounds__(256) void cast_transpose_k(const float* __restrict__ W,
    unsigned short* __restrict__ WT, int N)
{
  __shared__ float tile[64][65];
  int n0 = blockIdx.x * 64, k0 = blockIdx.y * 64;
  int tid = threadIdx.x;
  for (int i = tid; i < 4096; i += 256) {
    int r = i >> 6, c = i & 63;
    tile[r][c] = W[(k0 + r) * N + n0 + c];
  }
  __syncthreads();
  for (int i = tid; i < 1024; i += 256) {
    int r = i >> 4, c4 = (i & 15) * 4;
    ushort4 o;
    o.x = f2bf(tile[c4 + 0][r]); o.y = f2bf(tile[c4 + 1][r]);
    o.z = f2bf(tile[c4 + 2][r]); o.w = f2bf(tile[c4 + 3][r]);
    *reinterpret_cast<ushort4*>(&WT[(n0 + r) * 1024 + k0 + c4]) = o;
  }
}

// wq/wk/wv/wo fused cast+transpose (z selects)
__global__ __launch_bounds__(256) void cast_w4(const float* __restrict__ W0,
    const float* __restrict__ W1, const float* __restrict__ W2, const float* __restrict__ W3,
    unsigned short* __restrict__ T0, unsigned short* __restrict__ T1,
    unsigned short* __restrict__ T2, unsigned short* __restrict__ T3)
{
  int z = blockIdx.z;
  const float* W = (z == 0) ? W0 : (z == 1) ? W1 : (z == 2) ? W2 : W3;
  unsigned short* WT = (z == 0) ? T0 : (z == 1) ? T1 : (z == 2) ? T2 : T3;
  __shared__ float tile[64][65];
  int n0 = blockIdx.x * 64, k0 = blockIdx.y * 64;
  int tid = threadIdx.x;
  for (int i = tid; i < 4096; i += 256) {
    int r = i >> 6, c = i & 63;
    tile[r][c] = W[(k0 + r) * 1024 + n0 + c];
  }
  __syncthreads();
  for (int i = tid; i < 1024; i += 256) {
    int r = i >> 4, c4 = (i & 15) * 4;
    ushort4 o;
    o.x = f2bf(tile[c4 + 0][r]); o.y = f2bf(tile[c4 + 1][r]);
    o.z = f2bf(tile[c4 + 2][r]); o.w = f2bf(tile[c4 + 3][r]);
    *reinterpret_cast<ushort4*>(&WT[(n0 + r) * 1024 + k0 + c4]) = o;
  }
}

// X f32 [nmats][64][64] -> XT bf16 [nmats][e][dp] (per-matrix transpose)
__global__ __launch_bounds__(256) void fm_cast_t(const float* __restrict__ FM,
    unsigned short* __restrict__ FMT)
{
  __shared__ float tile[64][65];
  int b = blockIdx.x, tid = threadIdx.x;
  const float* src = FM + b * 4096;
  for (int i = tid; i < 4096; i += 256) tile[i >> 6][i & 63] = src[i];
  __syncthreads();
  unsigned short* dst = FMT + b * 4096;
  for (int i = tid; i < 4096; i += 256) {
    int e = i >> 6, dp = i & 63;
    dst[e * 64 + dp] = f2bf(tile[dp][e]);
  }
}

// ---------------- bf16 MFMA GEMM: C[M][ldc] = A[M][1024] x BT[N][1024]^T ----
__global__ __launch_bounds__(256) void mm_bf16(const unsigned short* __restrict__ A,
    const unsigned short* __restrict__ BT, float* __restrict__ C, int ldc, int act)
{
  __shared__ unsigned short As[128 * LDK];
  __shared__ unsigned short Bs[128 * LDK];
  int tid = threadIdx.x;
  int m0 = blockIdx.y * 128, n0 = blockIdx.x * 128;
  int wid = tid >> 6, lane = tid & 63;
  int wr = wid >> 1, wc = wid & 1;
  int lr = lane & 15, lg = lane >> 4;

  f32x4 acc[4][4];
#pragma unroll
  for (int m = 0; m < 4; ++m)
#pragma unroll
    for (int n = 0; n < 4; ++n)
#pragma unroll
      for (int r = 0; r < 4; ++r) acc[m][n][r] = 0.f;

  for (int kt = 0; kt < 16; ++kt) {
    int k0 = kt * 64;
#pragma unroll
    for (int p = 0; p < 4; ++p) {
      int c = p * 256 + tid;
      int row = c >> 3, k8 = c & 7;
      u16x8 va = *reinterpret_cast<const u16x8*>(A + (m0 + row) * 1024 + k0 + k8 * 8);
      *reinterpret_cast<u16x8*>(&As[row * LDK + k8 * 8]) = va;
      u16x8 vb = *reinterpret_cast<const u16x8*>(BT + (n0 + row) * 1024 + k0 + k8 * 8);
      *reinterpret_cast<u16x8*>(&Bs[row * LDK + k8 * 8]) = vb;
    }
    __syncthreads();
#pragma unroll
    for (int kk = 0; kk < 2; ++kk) {
      bf16x8 af[4], bfr[4];
#pragma unroll
      for (int m = 0; m < 4; ++m)
        af[m] = *reinterpret_cast<const bf16x8*>(&As[(wr * 64 + m * 16 + lr) * LDK + kk * 32 + lg * 8]);
#pragma unroll
      for (int n = 0; n < 4; ++n)
        bfr[n] = *reinterpret_cast<const bf16x8*>(&Bs[(wc * 64 + n * 16 + lr) * LDK + kk * 32 + lg * 8]);
#pragma unroll
      for (int m = 0; m < 4; ++m)
#pragma unroll
        for (int n = 0; n < 4; ++n)
          acc[m][n] = __builtin_amdgcn_mfma_f32_16x16x32_bf16(af[m], bfr[n], acc[m][n], 0, 0, 0);
    }
    __syncthreads();
  }
#pragma unroll
  for (int m = 0; m < 4; ++m)
#pragma unroll
    for (int n = 0; n < 4; ++n)
#pragma unroll
      for (int r = 0; r < 4; ++r) {
        float v = acc[m][n][r];
        if (act) v = v > 0.f ? v + 1.f : expf(v);
        C[(m0 + wr * 64 + m * 16 + lg * 4 + r) * ldc + n0 + wc * 64 + n * 16 + lr] = v;
      }
}

// fused QKV projections (z = q/k/v) -> bf16 outputs directly
__global__ __launch_bounds__(256) void proj_bf16(const unsigned short* __restrict__ A,
    const unsigned short* __restrict__ WqT, const unsigned short* __restrict__ WkT,
    const unsigned short* __restrict__ WvT,
    unsigned short* __restrict__ Oq, unsigned short* __restrict__ Ok,
    unsigned short* __restrict__ Ov)
{
  int z = blockIdx.z;
  const unsigned short* BT = (z == 0) ? WqT : (z == 1) ? WkT : WvT;
  unsigned short* C = (z == 0) ? Oq : (z == 1) ? Ok : Ov;

  __shared__ unsigned short As[128 * LDK];
  __shared__ unsigned short Bs[128 * LDK];
  int tid = threadIdx.x;
  int m0 = blockIdx.y * 128, n0 = blockIdx.x * 128;
  int wid = tid >> 6, lane = tid & 63;
  int wr = wid >> 1, wc = wid & 1;
  int lr = lane & 15, lg = lane >> 4;
  int act = (z < 2) ? 1 : 0;

  f32x4 acc[4][4];
#pragma unroll
  for (int m = 0; m < 4; ++m)
#pragma unroll
    for (int n = 0; n < 4; ++n)
#pragma unroll
      for (int r = 0; r < 4; ++r) acc[m][n][r] = 0.f;

  for (int kt = 0; kt < 16; ++kt) {
    int k0 = kt * 64;
#pragma unroll
    for (int p = 0; p < 4; ++p) {
      int c = p * 256 + tid;
      int row = c >> 3, k8 = c & 7;
      u16x8 va = *reinterpret_cast<const u16x8*>(A + (m0 + row) * 1024 + k0 + k8 * 8);
      *reinterpret_cast<u16x8*>(&As[row * LDK + k8 * 8]) = va;
      u16x8 vb = *reinterpret_cast<const u16x8*>(BT + (n0 + row) * 1024 + k0 + k8 * 8);
      *reinterpret_cast<u16x8*>(&Bs[row * LDK + k8 * 8]) = vb;
    }
    __syncthreads();
#pragma unroll
    for (int kk = 0; kk < 2; ++kk) {
      bf16x8 af[4], bfr[4];
#pragma unroll
      for (int m = 0; m < 4; ++m)
        af[m] = *reinterpret_cast<const bf16x8*>(&As[(wr * 64 + m * 16 + lr) * LDK + kk * 32 + lg * 8]);
#pragma unroll
      for (int n = 0; n < 4; ++n)
        bfr[n] = *reinterpret_cast<const bf16x8*>(&Bs[(wc * 64 + n * 16 + lr) * LDK + kk * 32 + lg * 8]);
#pragma unroll
      for (int m = 0; m < 4; ++m)
#pragma unroll
        for (int n = 0; n < 4; ++n)
          acc[m][n] = __builtin_amdgcn_mfma_f32_16x16x32_bf16(af[m], bfr[n], acc[m][n], 0, 0, 0);
    }
    __syncthreads();
  }
#pragma unroll
  for (int m = 0; m < 4; ++m)
#pragma unroll
    for (int n = 0; n < 4; ++n)
#pragma unroll
      for (int r = 0; r < 4; ++r) {
        float v = acc[m][n][r];
        if (act) v = v > 0.f ? v + 1.f : expf(v);
        C[(m0 + wr * 64 + m * 16 + lg * 4 + r) * 1024 + n0 + wc * 64 + n * 16 + lr] = f2bf(v);
      }
}

// ---------------- eg stage 2 ------------------------------------------------
__global__ __launch_bounds__(256) void eg_fin(const float* __restrict__ H1,
    const float* __restrict__ B1, const float* __restrict__ W2,
    const float* __restrict__ B2, float* __restrict__ EP)
{
  int wid = threadIdx.x >> 6, lane = threadIdx.x & 63;
  int s = blockIdx.x * 4 + wid;
  float4 h = *reinterpret_cast<const float4*>(H1 + s * 256 + lane * 4);
  float4 b = *reinterpret_cast<const float4*>(B1 + lane * 4);
  float4 w = *reinterpret_cast<const float4*>(W2 + lane * 4);
  float v = fmaxf(h.x + b.x, 0.f) * w.x + fmaxf(h.y + b.y, 0.f) * w.y
          + fmaxf(h.z + b.z, 0.f) * w.z + fmaxf(h.w + b.w, 0.f) * w.w;
  v = wave_allsum(v);
  if (lane == 0) EP[s] = 1.f / (1.f + expf(-(v + B2[0])));
}

// ---------------- rels: relevance dots (fp32 math, bf16 sigma_q) ------------
__global__ __launch_bounds__(256) void rels_kernel(const unsigned short* __restrict__ SQB,
    const float* __restrict__ ZC, const float* __restrict__ FN,
    float* __restrict__ RELC, float* __restrict__ RELS, float* __restrict__ PARTS)
{
  int h = blockIdx.x, st = blockIdx.y, tid = threadIdx.x;
  int s0 = st * 64;
  __shared__ float sqT[64][68];
  __shared__ float zf[5][64];
  __shared__ float relb[5][64];
#pragma unroll
  for (int p = 0; p < 2; ++p) {
    int cidx = p * 256 + tid;               // 512 chunks of 8
    int r = cidx >> 3, d8 = cidx & 7;
    u16x8 v = *reinterpret_cast<const u16x8*>(SQB + (s0 + r) * 1024 + h * 64 + d8 * 8);
#pragma unroll
    for (int j = 0; j < 8; ++j) sqT[d8 * 8 + j][r] = bf2f((unsigned short)v[j]);
  }
  for (int idx = tid; idx < 320; idx += 256) {
    int w = idx >> 6, d = idx & 63;
    zf[w][d] = (w == 0) ? ZC[h * 64 + d] : FN[(w - 1) * 1024 + h * 64 + d];
  }
  __syncthreads();
  {
    int s = tid & 63, wh = tid >> 6;
    float r = 0.f;
    for (int dp = 0; dp < 64; ++dp) r += sqT[dp][s] * zf[wh][dp];
    relb[wh][s] = r;
    if (wh == 0) {
      float r4 = 0.f;
      for (int dp = 0; dp < 64; ++dp) r4 += sqT[dp][s] * zf[4][dp];
      relb[4][s] = r4;
    }
  }
  __syncthreads();
  if (tid < 64) {
    RELC[h * 2048 + s0 + tid] = relb[0][tid];
#pragma unroll
    for (int f = 0; f < 4; ++f)
      RELS[f * 32768 + h * 2048 + s0 + tid] = relb[1 + f][tid];
#pragma unroll
    for (int f = 0; f < 4; ++f) {
      float v = wave_allsum(relb[1 + f][tid]);
      if (tid == 0) PARTS[f * 512 + h * 32 + st] = v;
    }
  }
}

// ---------------- coarse retrieval, bf16 MFMA (+fused cob cast) -------------
__global__ __launch_bounds__(256) void coarse_mfma(const unsigned short* __restrict__ SQB,
    const unsigned short* __restrict__ MCT, const float* __restrict__ RELC,
    float* __restrict__ CO, unsigned short* __restrict__ COB)
{
  int h = blockIdx.x, st = blockIdx.y, tid = threadIdx.x;
  int w = tid >> 6, lane = tid & 63, lr = lane & 15, lg = lane >> 4;
  int s0 = st * 128;
  __shared__ unsigned short A_lds[128 * LDK];
  __shared__ unsigned short B_lds[64 * LDK];
#pragma unroll
  for (int p = 0; p < 4; ++p) {
    int c = p * 256 + tid;
    int row = c >> 3, k8 = c & 7;
    *reinterpret_cast<u16x8*>(&A_lds[row * LDK + k8 * 8]) =
        *reinterpret_cast<const u16x8*>(SQB + (s0 + row) * 1024 + h * 64 + k8 * 8);
  }
#pragma unroll
  for (int p = 0; p < 2; ++p) {
    int c = p * 256 + tid;
    int e = c >> 3, k8 = c & 7;
    *reinterpret_cast<u16x8*>(&B_lds[e * LDK + k8 * 8]) =
        *reinterpret_cast<const u16x8*>(MCT + h * 4096 + e * 64 + k8 * 8);
  }
  __syncthreads();

  f32x4 acc[2][4];
#pragma unroll
  for (int m = 0; m < 2; ++m)
#pragma unroll
    for (int n = 0; n < 4; ++n)
#pragma unroll
      for (int r = 0; r < 4; ++r) acc[m][n][r] = 0.f;

#pragma unroll
  for (int kk = 0; kk < 2; ++kk) {
    bf16x8 af[2], bfr[4];
#pragma unroll
    for (int m = 0; m < 2; ++m)
      af[m] = *reinterpret_cast<const bf16x8*>(&A_lds[(w * 32 + m * 16 + lr) * LDK + kk * 32 + lg * 8]);
#pragma unroll
    for (int n = 0; n < 4; ++n)
      bfr[n] = *reinterpret_cast<const bf16x8*>(&B_lds[(n * 16 + lr) * LDK + kk * 32 + lg * 8]);
#pragma unroll
    for (int m = 0; m < 2; ++m)
#pragma unroll
      for (int n = 0; n < 4; ++n)
        acc[m][n] = __builtin_amdgcn_mfma_f32_16x16x32_bf16(af[m], bfr[n], acc[m][n], 0, 0, 0);
  }
#pragma unroll
  for (int m = 0; m < 2; ++m)
#pragma unroll
    for (int r = 0; r < 4; ++r) {
      int s = s0 + w * 32 + m * 16 + lg * 4 + r;
      float rc = fmaxf(RELC[h * 2048 + s], EPSF);
#pragma unroll
      for (int n = 0; n < 4; ++n) {
        float v = acc[m][n][r] / rc;
        CO[s * 1024 + h * 64 + n * 16 + lr] = v;
        COB[s * 1024 + h * 64 + n * 16 + lr] = f2bf(v);
      }
    }
}

// ---------------- K4: bank softmax weights ----------------------------------
__global__ void weights_kernel(const float* __restrict__ P, float* __restrict__ W)
{
  int h = threadIdx.x;
  if (h >= 16) return;
  float r[4];
#pragma unroll
  for (int f = 0; f < 4; ++f) {
    float s = 0.f;
    for (int t = 0; t < 32; ++t) s += P[f * 512 + h * 32 + t];
    r[f] = s * (1.f / 2048.f);
  }
  float m = fmaxf(fmaxf(r[0], r[1]), fmaxf(r[2], r[3]));
  float e0 = expf(r[0] - m), e1 = expf(r[1] - m), e2 = expf(r[2] - m), e3 = expf(r[3] - m);
  float inv = 1.f / (e0 + e1 + e2 + e3);
  W[0 * 16 + h] = e0 * inv; W[1 * 16 + h] = e1 * inv;
  W[2 * 16 + h] = e2 * inv; W[3 * 16 + h] = e3 * inv;
}

// ---------------- fine retrieval + combine, bf16 MFMA -----------------------
__global__ __launch_bounds__(256) void fine_mfma(const unsigned short* __restrict__ SQB,
    const unsigned short* __restrict__ FMT, const float* __restrict__ RELS,
    const float* __restrict__ WT, const float* __restrict__ EP,
    const float* __restrict__ CO, float* __restrict__ MO)
{
  int h = blockIdx.x, st = blockIdx.y;
  int tid = threadIdx.x;
  int w = tid >> 6, lane = tid & 63;
  int lr = lane & 15, lg = lane >> 4;
  int s0 = st * 128;

  __shared__ unsigned short A_lds[128 * LDK];
  __shared__ unsigned short B_lds[4 * 64 * LDK];
  __shared__ float w4s[4];
  if (tid < 4) w4s[tid] = WT[tid * 16 + h];

#pragma unroll
  for (int p = 0; p < 4; ++p) {
    int c = p * 256 + tid;
    int row = c >> 3, k8 = c & 7;
    *reinterpret_cast<u16x8*>(&A_lds[row * LDK + k8 * 8]) =
        *reinterpret_cast<const u16x8*>(SQB + (s0 + row) * 1024 + h * 64 + k8 * 8);
  }
#pragma unroll
  for (int p = 0; p < 8; ++p) {
    int c = p * 256 + tid;
    int f = c >> 9, rem = c & 511;
    int e = rem >> 3, k8 = rem & 7;
    *reinterpret_cast<u16x8*>(&B_lds[(f * 64 + e) * LDK + k8 * 8]) =
        *reinterpret_cast<const u16x8*>(FMT + (f * 16 + h) * 4096 + e * 64 + k8 * 8);
  }
  __syncthreads();

  f32x4 acc[4][2][4];
#pragma unroll
  for (int f = 0; f < 4; ++f)
#pragma unroll
    for (int m = 0; m < 2; ++m)
#pragma unroll
      for (int n = 0; n < 4; ++n)
#pragma unroll
        for (int r = 0; r < 4; ++r) acc[f][m][n][r] = 0.f;

#pragma unroll
  for (int kk = 0; kk < 2; ++kk) {
    bf16x8 af[2];
#pragma unroll
    for (int m = 0; m < 2; ++m)
      af[m] = *reinterpret_cast<const bf16x8*>(&A_lds[(w * 32 + m * 16 + lr) * LDK + kk * 32 + lg * 8]);
#pragma unroll
    for (int f = 0; f < 4; ++f) {
      bf16x8 bf4[4];
#pragma unroll
      for (int n = 0; n < 4; ++n)
        bf4[n] = *reinterpret_cast<const bf16x8*>(&B_lds[(f * 64 + n * 16 + lr) * LDK + kk * 32 + lg * 8]);
#pragma unroll
      for (int m = 0; m < 2; ++m)
#pragma unroll
        for (int n = 0; n < 4; ++n)
          acc[f][m][n] = __builtin_amdgcn_mfma_f32_16x16x32_bf16(af[m], bf4[n], acc[f][m][n], 0, 0, 0);
    }
  }

#pragma unroll
  for (int m = 0; m < 2; ++m)
#pragma unroll
    for (int r = 0; r < 4; ++r) {
      int s = s0 + w * 32 + m * 16 + lg * 4 + r;
      float e = EP[s];
      float i0 = w4s[0] / fmaxf(RELS[0 * 32768 + h * 2048 + s], EPSF);
      float i1 = w4s[1] / fmaxf(RELS[1 * 32768 + h * 2048 + s], EPSF);
      float i2 = w4s[2] / fmaxf(RELS[2 * 32768 + h * 2048 + s], EPSF);
      float i3 = w4s[3] / fmaxf(RELS[3 * 32768 + h * 2048 + s], EPSF);
#pragma unroll
      for (int n = 0; n < 4; ++n) {
        int dg = h * 64 + n * 16 + lr;
        float fine = acc[0][m][n][r] * i0 + acc[1][m][n][r] * i1
                   + acc[2][m][n][r] * i2 + acc[3][m][n][r] * i3;
        float cv = CO[s * 1024 + dg];
        MO[s * 1024 + dg] = e * fine + (1.f - e) * cv;
      }
    }
}

// ---------------- chunk KV states, bf16 MFMA (ksum as ones-column) ----------
// ST[d][e] = sum_s sk[s][d]*vv[s][e]; col 64 = sum_s sk[s][d].
__global__ __launch_bounds__(256) void chunk_mfma(const unsigned short* __restrict__ SKB,
    const unsigned short* __restrict__ VVB, float* __restrict__ ST)
{
  int h = blockIdx.x, c = blockIdx.y, tid = threadIdx.x;
  int w = tid >> 6, lane = tid & 63, lr = lane & 15, lg = lane >> 4;
  int sb = c * 64;
  __shared__ unsigned short A_lds[64 * LDK];   // sk^T [d][s]
  __shared__ unsigned short B_lds[80 * LDK];   // v^T [e][s]; row64=ones; 65-79=0
#pragma unroll
  for (int p = 0; p < 2; ++p) {
    int cc = p * 256 + tid;
    int t = cc >> 3, e8 = cc & 7;
    u16x8 kv = *reinterpret_cast<const u16x8*>(SKB + (sb + t) * 1024 + h * 64 + e8 * 8);
    u16x8 vv = *reinterpret_cast<const u16x8*>(VVB + (sb + t) * 1024 + h * 64 + e8 * 8);
#pragma unroll
    for (int j = 0; j < 8; ++j) {
      A_lds[(e8 * 8 + j) * LDK + t] = (unsigned short)kv[j];
      B_lds[(e8 * 8 + j) * LDK + t] = (unsigned short)vv[j];
    }
  }
  if (tid < 64) B_lds[64 * LDK + tid] = 0x3F80;
  for (int i = tid; i < 15 * 64; i += 256) {
    int row = 65 + (i >> 6), col = i & 63;
    B_lds[row * LDK + col] = 0;
  }
  __syncthreads();

  f32x4 acc[5];
#pragma unroll
  for (int n = 0; n < 5; ++n)
#pragma unroll
    for (int r = 0; r < 4; ++r) acc[n][r] = 0.f;
#pragma unroll
  for (int kk = 0; kk < 2; ++kk) {
    bf16x8 af = *reinterpret_cast<const bf16x8*>(&A_lds[(w * 16 + lr) * LDK + kk * 32 + lg * 8]);
#pragma unroll
    for (int n = 0; n < 5; ++n) {
      bf16x8 bfr = *reinterpret_cast<const bf16x8*>(&B_lds[(n * 16 + lr) * LDK + kk * 32 + lg * 8]);
      acc[n] = __builtin_amdgcn_mfma_f32_16x16x32_bf16(af, bfr, acc[n], 0, 0, 0);
    }
  }
  float* base = ST + (h * 32 + c) * 4160;
#pragma unroll
  for (int r = 0; r < 4; ++r) {
    int d = w * 16 + lg * 4 + r;
#pragma unroll
    for (int n = 0; n < 4; ++n)
      base[d * 64 + n * 16 + lr] = acc[n][r];
    if (lr == 0) base[4096 + d] = acc[4][r];
  }
}

// ---------------- scan: exclusive prefix, f32 in -> bf16 out ----------------
__global__ __launch_bounds__(256) void scan_kernel(const float* __restrict__ ST,
    unsigned short* __restrict__ STB)
{
  int gidx = blockIdx.x * 256 + threadIdx.x;
  int h = gidx / 4160, idx = gidx - h * 4160;
  if (h >= 16) return;
  float run = 0.f;
#pragma unroll 4
  for (int c = 0; c < 32; ++c) {
    float t = ST[(h * 32 + c) * 4160 + idx];
    STB[(h * 32 + c) * 4160 + idx] = f2bf(run);
    run += t;
  }
}

// ---------------- causal linear attention, bf16 MFMA ------------------------
__global__ __launch_bounds__(256) void lattn_mfma(const unsigned short* __restrict__ SQB,
    const unsigned short* __restrict__ SKB, const unsigned short* __restrict__ VVB,
    const unsigned short* __restrict__ STB, float* __restrict__ OUT)
{
  int h = blockIdx.x, c = blockIdx.y, tid = threadIdx.x;
  int w = tid >> 6, lane = tid & 63, lr = lane & 15, lg = lane >> 4;
  int sb = c * 64;
  const unsigned short* stb = STB + (h * 32 + c) * 4160;

  __shared__ unsigned short A_lds[64 * LDK];   // sigma_q rows
  __shared__ unsigned short K_lds[64 * LDK];   // sigma_k rows
  __shared__ unsigned short P_lds[80 * LDK];   // KVprev^T rows; row64=kprev
  __shared__ unsigned short V_lds[80 * LDK];   // v^T rows; row64=ones
  __shared__ unsigned short S_lds[64 * LDK];   // masked scores

#pragma unroll
  for (int p = 0; p < 2; ++p) {
    int cc = p * 256 + tid;
    int row = cc >> 3, k8 = cc & 7;
    *reinterpret_cast<u16x8*>(&A_lds[row * LDK + k8 * 8]) =
        *reinterpret_cast<const u16x8*>(SQB + (sb + row) * 1024 + h * 64 + k8 * 8);
    *reinterpret_cast<u16x8*>(&K_lds[row * LDK + k8 * 8]) =
        *reinterpret_cast<const u16x8*>(SKB + (sb + row) * 1024 + h * 64 + k8 * 8);
  }
  for (int i = tid; i < 4096; i += 256) {          // KVprev [d][e] -> P[e][d]
    int d = i >> 6, e = i & 63;
    P_lds[e * LDK + d] = stb[i];
  }
#pragma unroll
  for (int p = 0; p < 2; ++p) {                    // v [t][e] -> V[e][t]
    int cc = p * 256 + tid;
    int t = cc >> 3, e8 = cc & 7;
    u16x8 v = *reinterpret_cast<const u16x8*>(VVB + (sb + t) * 1024 + h * 64 + e8 * 8);
#pragma unroll
    for (int j = 0; j < 8; ++j) V_lds[(e8 * 8 + j) * LDK + t] = (unsigned short)v[j];
  }
  if (tid < 64) {
    P_lds[64 * LDK + tid] = stb[4096 + tid];       // kprev
    V_lds[64 * LDK + tid] = 0x3F80;                // ones (bf16 1.0)
  }
  for (int i = tid; i < 15 * 64; i += 256) {       // zero pad rows 65..79
    int row = 65 + (i >> 6), col = i & 63;
    P_lds[row * LDK + col] = 0;
    V_lds[row * LDK + col] = 0;
  }
  __syncthreads();

  // phase A: inter-chunk num + den (k = d)
  f32x4 acc_i[5];
#pragma unroll
  for (int n = 0; n < 5; ++n)
#pragma unroll
    for (int r = 0; r < 4; ++r) acc_i[n][r] = 0.f;
#pragma unroll
  for (int kk = 0; kk < 2; ++kk) {
    bf16x8 af = *reinterpret_cast<const bf16x8*>(&A_lds[(w * 16 + lr) * LDK + kk * 32 + lg * 8]);
#pragma unroll
    for (int n = 0; n < 5; ++n) {
      bf16x8 bfr = *reinterpret_cast<const bf16x8*>(&P_lds[(n * 16 + lr) * LDK + kk * 32 + lg * 8]);
      acc_i[n] = __builtin_amdgcn_mfma_f32_16x16x32_bf16(af, bfr, acc_i[n], 0, 0, 0);
    }
  }
  // phase B: scores (k = d)
  f32x4 acc_s[4];
#pragma unroll
  for (int n = 0; n < 4; ++n)
#pragma unroll
    for (int r = 0; r < 4; ++r) acc_s[n][r] = 0.f;
#pragma unroll
  for (int kk = 0; kk < 2; ++kk) {
    bf16x8 af = *reinterpret_cast<const bf16x8*>(&A_lds[(w * 16 + lr) * LDK + kk * 32 + lg * 8]);
#pragma unroll
    for (int n = 0; n < 4; ++n) {
      bf16x8 bfr = *reinterpret_cast<const bf16x8*>(&K_lds[(n * 16 + lr) * LDK + kk * 32 + lg * 8]);
      acc_s[n] = __builtin_amdgcn_mfma_f32_16x16x32_bf16(af, bfr, acc_s[n], 0, 0, 0);
    }
  }
  // mask + write S (causal within chunk: t <= s)
#pragma unroll
  for (int n = 0; n < 4; ++n)
#pragma unroll
    for (int r = 0; r < 4; ++r) {
      int s_loc = w * 16 + lg * 4 + r, t = n * 16 + lr;
      float v = (t <= s_loc) ? acc_s[n][r] : 0.f;
      S_lds[s_loc * LDK + t] = f2bf(v);
    }
  __syncthreads();
  // phase C: PV + intra den (k = t)
  f32x4 acc_p[5];
#pragma unroll
  for (int n = 0; n < 5; ++n)
#pragma unroll
    for (int r = 0; r < 4; ++r) acc_p[n][r] = 0.f;
#pragma unroll
  for (int kk = 0; kk < 2; ++kk) {
    bf16x8 af = *reinterpret_cast<const bf16x8*>(&S_lds[(w * 16 + lr) * LDK + kk * 32 + lg * 8]);
#pragma unroll
    for (int n = 0; n < 5; ++n) {
      bf16x8 bfr = *reinterpret_cast<const bf16x8*>(&V_lds[(n * 16 + lr) * LDK + kk * 32 + lg * 8]);
      acc_p[n] = __builtin_amdgcn_mfma_f32_16x16x32_bf16(af, bfr, acc_p[n], 0, 0, 0);
    }
  }
  // epilogue
#pragma unroll
  for (int r = 0; r < 4; ++r) {
    float den = acc_i[4][r] + acc_p[4][r];
    den = __shfl(den, lane & 48);
    den = fmaxf(den, EPSF);
    int s = sb + w * 16 + lg * 4 + r;
#pragma unroll
    for (int n = 0; n < 4; ++n)
      OUT[s * 1024 + h * 64 + n * 16 + lr] = (acc_i[n][r] + acc_p[n][r]) / den;
  }
}

// ---------------- gate combine -> bf16 --------------------------------------
__global__ __launch_bounds__(256) void combine_bf16(const float* __restrict__ MO,
    const float* __restrict__ LO, const float* __restrict__ MG,
    unsigned short* __restrict__ CBB)
{
  int i = blockIdx.x * 256 + threadIdx.x;
  float4 m4 = *reinterpret_cast<const float4*>(MO + i * 4);
  float4 l4 = *reinterpret_cast<const float4*>(LO + i * 4);
  int hh = ((i * 4) >> 6) & 15;
  float g = 1.f / (1.f + expf(-MG[hh]));
  ushort4 o;
  o.x = f2bf(g * m4.x + (1.f - g) * l4.x);
  o.y = f2bf(g * m4.y + (1.f - g) * l4.y);
  o.z = f2bf(g * m4.z + (1.f - g) * l4.z);
  o.w = f2bf(g * m4.w + (1.f - g) * l4.w);
  *reinterpret_cast<ushort4*>(CBB + i * 4) = o;
}

// ---------------------------------------------------------------------------
extern "C" void kernel_launch(void* const* d_in, const int* in_sizes, int n_in,
                              void* d_out, int out_size, void* d_ws, size_t ws_size,
                              hipStream_t stream)
{
  const float* hs   = (const float*)d_in[0];
  const float* wq   = (const float*)d_in[1];
  const float* wk   = (const float*)d_in[2];
  const float* wv   = (const float*)d_in[3];
  const float* wo   = (const float*)d_in[4];
  const float* mg   = (const float*)d_in[5];
  const float* egw1 = (const float*)d_in[6];
  const float* egb1 = (const float*)d_in[7];
  const float* egw2 = (const float*)d_in[8];
  const float* egb2 = (const float*)d_in[9];
  const float* fm   = (const float*)d_in[10];
  const float* fn   = (const float*)d_in[11];
  float* out = (float*)d_out;

  // ---- disjoint workspace layout (~70 MB of 268 MB) ----
  float* ws     = (float*)d_ws;
  float* co     = ws;                       // [2048][1024] f32
  float* mo     = co + 2097152;
  float* lo     = mo + 2097152;
  float* zc     = lo + 2097152;             // 1024
  float* rels   = zc + 1024;                // 131072
  float* parts  = rels + 131072;            // 2048
  float* wts    = parts + 2048;             // 64
  float* ep     = wts + 64;                 // 2048
  float* relc   = ep + 2048;                // 32768
  float* states = relc + 32768;             // 2129920
  float* h1     = states + 2129920;         // 524288
  unsigned short* hsb  = (unsigned short*)(h1 + 524288);   // 2097152 each
  unsigned short* sqb  = hsb + 2097152;
  unsigned short* skb  = sqb + 2097152;
  unsigned short* vvb  = skb + 2097152;
  unsigned short* cob  = vvb + 2097152;
  unsigned short* cbb  = cob + 2097152;
  unsigned short* wqT  = cbb + 2097152;     // 1048576 each
  unsigned short* wkT  = wqT + 1048576;
  unsigned short* wvT  = wkT + 1048576;
  unsigned short* woT  = wvT + 1048576;
  unsigned short* w1T  = woT + 1048576;     // 262144
  unsigned short* fmbT = w1T + 262144;      // 262144
  unsigned short* mcT  = fmbT + 262144;     // 65536
  unsigned short* statesb = mcT + 65536;    // 2129920

  k0_mcT<<<16, 256, 0, stream>>>(fm, fn, mcT, zc);
  cast_w4<<<dim3(16, 16, 4), 256, 0, stream>>>(wq, wk, wv, wo, wqT, wkT, wvT, woT);
  cast_transpose_k<<<dim3(4, 16), 256, 0, stream>>>(egw1, w1T, 256);
  fm_cast_t<<<64, 256, 0, stream>>>(fm, fmbT);
  cast_bf16_k<<<2048, 256, 0, stream>>>(hs, hsb);
  proj_bf16<<<dim3(8, 16, 3), 256, 0, stream>>>(hsb, wqT, wkT, wvT, sqb, skb, vvb);
  rels_kernel<<<dim3(16, 32), 256, 0, stream>>>(sqb, zc, fn, relc, rels, parts);
  coarse_mfma<<<dim3(16, 16), 256, 0, stream>>>(sqb, mcT, relc, co, cob);
  mm_bf16<<<dim3(2, 16), 256, 0, stream>>>(cob, w1T, h1, 256, 0);   // eg stage 1
  eg_fin<<<512, 256, 0, stream>>>(h1, egb1, egw2, egb2, ep);
  weights_kernel<<<1, 64, 0, stream>>>(parts, wts);
  fine_mfma<<<dim3(16, 16), 256, 0, stream>>>(sqb, fmbT, rels, wts, ep, co, mo);
  chunk_mfma<<<dim3(16, 32), 256, 0, stream>>>(skb, vvb, states);
  scan_kernel<<<260, 256, 0, stream>>>(states, statesb);
  lattn_mfma<<<dim3(16, 32), 256, 0, stream>>>(sqb, skb, vvb, statesb, lo);
  combine_bf16<<<2048, 256, 0, stream>>>(mo, lo, mg, cbb);
  mm_bf16<<<dim3(8, 16), 256, 0, stream>>>(cbb, woT, out, 1024, 0);
}